// Round 10
// baseline (1897.734 us; speedup 1.0000x reference)
//
#include <hip/hip_runtime.h>
#include <math.h>

#define HD 256
#define BATCH 1024
#define NSTEPS 64
#define DIN 4
#define MMETA 4
#define GE 4
#define NBLK (BATCH / GE)

typedef short bf16x8 __attribute__((ext_vector_type(8)));
typedef float f32x4 __attribute__((ext_vector_type(4)));
typedef unsigned u32x2 __attribute__((ext_vector_type(2)));
typedef unsigned u32x4 __attribute__((ext_vector_type(4)));

#define F(x) ((float)(x))
#define A21f F(0.2)
#define A31f F(3.0/40.0)
#define A32f F(9.0/40.0)
#define A41f F(44.0/45.0)
#define A42f F(-56.0/15.0)
#define A43f F(32.0/9.0)
#define A51f F(19372.0/6561.0)
#define A52f F(-25360.0/2187.0)
#define A53f F(64448.0/6561.0)
#define A54f F(-212.0/729.0)
#define A61f F(9017.0/3168.0)
#define A62f F(-355.0/33.0)
#define A63f F(46732.0/5247.0)
#define A64f F(49.0/176.0)
#define A65f F(-5103.0/18656.0)
#define BC0f F(35.0/384.0)
#define BC2f F(500.0/1113.0)
#define BC3f F(125.0/192.0)
#define BC4f F(-2187.0/6784.0)
#define BC5f F(11.0/84.0)
#define EC0f F(35.0/384.0 - 5179.0/57600.0)
#define EC2f F(500.0/1113.0 - 7571.0/16695.0)
#define EC3f F(125.0/192.0 - 393.0/640.0)
#define EC4f F(-2187.0/6784.0 + 92097.0/339200.0)
#define EC5f F(11.0/84.0 - 187.0/2100.0)
#define EC6f F(-1.0/40.0)

#define SELU_SCALE 1.0507009873554805f
#define SELU_SA    1.7580993408473766f   // scale*alpha

// activation row strides, chosen ≡16 mod 128 so the per-lane 16B chunk slot
// (byte%128)/16 = (m15 + 4ks + lg)%8 covers all 8 bank-groups evenly.
#define OZS 528    // ode zA: 264 shorts (256 data + pad)
#define GZS 544    // gru zB: 272 shorts (256 h + xm at 256-259,264-267 + pad)

__device__ __forceinline__ unsigned short f2bf(float f) {
    unsigned u = __float_as_uint(f);
    return (unsigned short)((u + 0x7fffu + ((u >> 16) & 1u)) >> 16);
}

__device__ __forceinline__ float selu_f(float v) {
    return v > 0.f ? SELU_SCALE * v : fmaf(SELU_SA, __expf(v), -SELU_SA);
}

// permuted storage position of k within a row: one ds_read_b128 yields the
// 8-elem fragment {k = ks*32 + (j>>2)*16 + lg*4 + (j&3)}.
__device__ __forceinline__ int pperm(int k) {
    return (k & ~31) | (((k >> 2) & 3) << 3) | (((k >> 4) & 1) << 2) | (k & 3);
}

// ---------------- generic transpose: in[R][C] -> out[C][R] ----------------
__global__ void transpose_kernel(const float* __restrict__ in, float* __restrict__ out,
                                 int R, int C) {
    int c = blockIdx.x * 256 + threadIdx.x;
    int r = blockIdx.y;
    if (c < C) out[c * R + r] = in[r * C + c];
}

// ---- pack W[NT*16][256] f32 into per-lane MFMA fragments -----------------
__global__ void pack_mfma_w(const float* __restrict__ W, unsigned* __restrict__ out) {
    int t = blockIdx.x * 256 + threadIdx.x;
    int lane = t & 63, ks = (t >> 6) & 7, nt = t >> 9;
    int n = nt * 16 + (lane & 15), lg = lane >> 4;
    const float* wr = W + n * HD;
    u32x4 v;
#pragma unroll
    for (int r = 0; r < 4; ++r) {
        int j0 = 2 * r, j1 = 2 * r + 1;
        int k0 = ks * 32 + ((j0 >> 2) << 4) + lg * 4 + (j0 & 3);
        int k1 = ks * 32 + ((j1 >> 2) << 4) + lg * 4 + (j1 & 3);
        v[r] = ((unsigned)f2bf(wr[k1]) << 16) | (unsigned)f2bf(wr[k0]);
    }
    *(u32x4*)(out + t * 4) = v;
}

// ---- pack Wih[768][8] into k=0..7-only fragments (48 nt, 1 ks tile) ------
__global__ void pack_wih(const float* __restrict__ W, unsigned* __restrict__ out) {
    int t = blockIdx.x * 256 + threadIdx.x;
    int lane = t & 63, nt = t >> 6;
    int n = nt * 16 + (lane & 15), lg = lane >> 4;
    u32x4 v;
#pragma unroll
    for (int r = 0; r < 4; ++r) {
        int j0 = 2 * r, j1 = 2 * r + 1;
        int k0 = ((j0 >> 2) << 4) + lg * 4 + (j0 & 3);
        int k1 = ((j1 >> 2) << 4) + lg * 4 + (j1 & 3);
        unsigned a = (k0 < 8) ? (unsigned)f2bf(W[n * 8 + k0]) : 0u;
        unsigned b = (k1 < 8) ? (unsigned)f2bf(W[n * 8 + k1]) : 0u;
        v[r] = (b << 16) | a;
    }
    *(u32x4*)(out + t * 4) = v;
}

// ---------------- GRU via MFMA: 256 blocks (G=4), 1024 threads ------------
__global__ __launch_bounds__(1024, 4) void gru_kernel(
    const float* __restrict__ x, const float* __restrict__ meta,
    const unsigned* __restrict__ WihF, const unsigned* __restrict__ WhhF,
    const float* __restrict__ bih, const float* __restrict__ bhh,
    float* __restrict__ h_out) {
    __shared__ short zB[16][GZS / 2];   // bf16 [m][pperm(k)]
    __shared__ float ghs[768][4];
    __shared__ float ghx[256][4];
    __shared__ float bsum[512], binn[256], bhn[256];

    const int tid  = threadIdx.x;
    const int lane = tid & 63;
    const int w    = tid >> 6;          // wave 0..15
    const int m15  = lane & 15;
    const int lg   = lane >> 4;
    const int b0   = blockIdx.x * 4;

    if (tid < 512) bsum[tid] = bih[tid] + bhh[tid];
    if (tid < 256) { binn[tid] = bih[512 + tid]; bhn[tid] = bhh[512 + tid]; }
    for (int i = tid; i < 16 * GZS / 4; i += 1024) ((unsigned*)zB)[i] = 0u;

    float h_own[4] = {0.f, 0.f, 0.f, 0.f};
    __syncthreads();

    // stage xm for step 0
    if (tid < 32) {
        int c = tid & 7, m = tid >> 3;
        float v = (c < 4) ? x[((b0 + m) * NSTEPS + 0) * DIN + c]
                          : meta[(b0 + m) * MMETA + (c - 4)];
        int pp = (c < 4) ? c : 8 + (c & 3);
        *(short*)((char*)zB + m * GZS + (256 + pp) * 2) = (short)f2bf(v);
    }

    for (int n = 0; n < NSTEPS; ++n) {
        __syncthreads();                // barrier A: zB (h + xm) ready
        bf16x8 zf[9];
#pragma unroll
        for (int ks = 0; ks < 9; ++ks)
            zf[ks] = *(const bf16x8*)((const char*)&zB[0][0] + m15 * GZS + ks * 64 + lg * 16);
#pragma unroll
        for (int jn = 0; jn < 3; ++jn) {
            const int nt = w * 3 + jn;
            const unsigned* bp = WhhF + (nt * 8) * 256 + lane * 4;
            f32x4 acc = {0.f, 0.f, 0.f, 0.f};
#pragma unroll
            for (int ks = 0; ks < 8; ++ks) {
                bf16x8 wf = *(const bf16x8*)(bp + ks * 256);
                acc = __builtin_amdgcn_mfma_f32_16x16x32_bf16(wf, zf[ks], acc, 0, 0, 0);
            }
            bf16x8 wih = *(const bf16x8*)(WihF + nt * 256 + lane * 4);
            if (nt < 32) {
                acc = __builtin_amdgcn_mfma_f32_16x16x32_bf16(wih, zf[8], acc, 0, 0, 0);
                if (m15 < 4) {
#pragma unroll
                    for (int r = 0; r < 4; ++r) ghs[nt * 16 + lg * 4 + r][m15] = acc[r];
                }
            } else {
                f32x4 ax = {0.f, 0.f, 0.f, 0.f};
                ax = __builtin_amdgcn_mfma_f32_16x16x32_bf16(wih, zf[8], ax, 0, 0, 0);
                if (m15 < 4) {
#pragma unroll
                    for (int r = 0; r < 4; ++r) {
                        int row = nt * 16 + lg * 4 + r;
                        ghs[row][m15] = acc[r];
                        ghx[row - 512][m15] = ax[r];
                    }
                }
            }
        }
        __syncthreads();                // barrier B: gh ready; zB reads done
        if (tid < 256) {
            f32x4 s0 = *(const f32x4*)(&ghs[tid][0]);
            f32x4 s1 = *(const f32x4*)(&ghs[tid + 256][0]);
            f32x4 hn = *(const f32x4*)(&ghs[tid + 512][0]);
            f32x4 in = *(const f32x4*)(&ghx[tid][0]);
            float bs0 = bsum[tid], bs1 = bsum[tid + 256];
            float bi2 = binn[tid], bh2 = bhn[tid];
            int pp2 = pperm(tid) * 2;
#pragma unroll
            for (int m = 0; m < 4; ++m) {
                float rr = 1.f / (1.f + expf(-(s0[m] + bs0)));
                float zz = 1.f / (1.f + expf(-(s1[m] + bs1)));
                float nn = tanhf((in[m] + bi2) + rr * (hn[m] + bh2));
                h_own[m] = (1.f - zz) * nn + zz * h_own[m];
                *(short*)((char*)zB + m * GZS + pp2) = (short)f2bf(h_own[m]);
            }
        }
        if (tid < 32 && n + 1 < NSTEPS) {
            int c = tid & 7, m = tid >> 3;
            float v = (c < 4) ? x[((b0 + m) * NSTEPS + (n + 1)) * DIN + c]
                              : meta[(b0 + m) * MMETA + (c - 4)];
            int pp = (c < 4) ? c : 8 + (c & 3);
            *(short*)((char*)zB + m * GZS + (256 + pp) * 2) = (short)f2bf(v);
        }
    }
    if (tid < 256) {
#pragma unroll
        for (int m = 0; m < 4; ++m) h_out[(b0 + m) * HD + tid] = h_own[m];
    }
}

// ---------------- encoder + reparameterization (G=8, 128 blocks) ----------
__global__ __launch_bounds__(256) void enc_kernel(
    const float* __restrict__ h_buf, const float* __restrict__ eps,
    const float* __restrict__ W1T, const float* __restrict__ b1,
    const float* __restrict__ W2T, const float* __restrict__ b2,
    float* __restrict__ y0_buf) {
    __shared__ float zsh[HD][8];
    const int tid = threadIdx.x;
    const int b0 = blockIdx.x * 8;
#pragma unroll
    for (int g = 0; g < 8; ++g) zsh[tid][g] = h_buf[(b0 + g) * HD + tid];
    __syncthreads();
    float acc[8];
    {
        float bb = b1[tid];
#pragma unroll
        for (int g = 0; g < 8; ++g) acc[g] = bb;
        for (int k = 0; k < HD; k += 4) {
#pragma unroll
            for (int u = 0; u < 4; ++u) {
                float w = W1T[(k + u) * HD + tid];
                const float4 za = *(const float4*)(&zsh[k + u][0]);
                const float4 zb = *(const float4*)(&zsh[k + u][4]);
                acc[0] = fmaf(w, za.x, acc[0]); acc[1] = fmaf(w, za.y, acc[1]);
                acc[2] = fmaf(w, za.z, acc[2]); acc[3] = fmaf(w, za.w, acc[3]);
                acc[4] = fmaf(w, zb.x, acc[4]); acc[5] = fmaf(w, zb.y, acc[5]);
                acc[6] = fmaf(w, zb.z, acc[6]); acc[7] = fmaf(w, zb.w, acc[7]);
            }
        }
    }
    __syncthreads();
#pragma unroll
    for (int g = 0; g < 8; ++g) zsh[tid][g] = fmaxf(acc[g], 0.f);
    __syncthreads();
    float am[8], as[8];
    {
        float bm = b2[tid], bs = b2[tid + HD];
#pragma unroll
        for (int g = 0; g < 8; ++g) { am[g] = bm; as[g] = bs; }
        for (int k = 0; k < HD; k += 4) {
#pragma unroll
            for (int u = 0; u < 4; ++u) {
                float wm = W2T[(k + u) * 512 + tid];
                float ws2 = W2T[(k + u) * 512 + HD + tid];
                const float4 za = *(const float4*)(&zsh[k + u][0]);
                const float4 zb = *(const float4*)(&zsh[k + u][4]);
                am[0] = fmaf(wm, za.x, am[0]); am[1] = fmaf(wm, za.y, am[1]);
                am[2] = fmaf(wm, za.z, am[2]); am[3] = fmaf(wm, za.w, am[3]);
                am[4] = fmaf(wm, zb.x, am[4]); am[5] = fmaf(wm, zb.y, am[5]);
                am[6] = fmaf(wm, zb.z, am[6]); am[7] = fmaf(wm, zb.w, am[7]);
                as[0] = fmaf(ws2, za.x, as[0]); as[1] = fmaf(ws2, za.y, as[1]);
                as[2] = fmaf(ws2, za.z, as[2]); as[3] = fmaf(ws2, za.w, as[3]);
                as[4] = fmaf(ws2, zb.x, as[4]); as[5] = fmaf(ws2, zb.y, as[5]);
                as[6] = fmaf(ws2, zb.z, as[6]); as[7] = fmaf(ws2, zb.w, as[7]);
            }
        }
    }
#pragma unroll
    for (int g = 0; g < 8; ++g)
        y0_buf[(b0 + g) * HD + tid] = eps[(b0 + g) * HD + tid] * as[g] + am[g];
}

// ---------- MFMA 4-layer MLP: W1 from LDS, W2-W4 streamed; 1 nt/wave ------
__device__ __forceinline__ void eval_mlp16(
    const unsigned* __restrict__ w1l, const unsigned* __restrict__ WPK,
    const float (*bias)[HD], short (*zA)[16 * OZS / 2], float* __restrict__ k4,
    int lane, int w, int m15, int lg) {
#pragma unroll
    for (int L = 0; L < 4; ++L) {
        __syncthreads();   // staged y' / previous epilogue visible; WAR safe
        const char* ibp = (const char*)&zA[L & 1][0];
        bf16x8 zf[8];
#pragma unroll
        for (int ks = 0; ks < 8; ++ks)
            zf[ks] = *(const bf16x8*)(ibp + m15 * OZS + ks * 64 + lg * 16);
        f32x4 a0 = {0.f, 0.f, 0.f, 0.f};
#pragma unroll
        for (int ks = 0; ks < 8; ++ks) {
            bf16x8 wf = (L == 0)
                ? *(const bf16x8*)(w1l + (w * 8 + ks) * 256 + lane * 4)
                : *(const bf16x8*)(WPK + ((L * 16 + w) * 8 + ks) * 256 + lane * 4);
            a0 = __builtin_amdgcn_mfma_f32_16x16x32_bf16(wf, zf[ks], a0, 0, 0, 0);
        }
        // D^T: lane holds col m=m15, rows n = w*16 + lg*4 + r
        const f32x4 bv = *(const f32x4*)(&bias[L][w * 16 + lg * 4]);
        if (L < 3) {
            float v0 = selu_f(a0[0] + bv[0]);
            float v1 = selu_f(a0[1] + bv[1]);
            float v2 = selu_f(a0[2] + bv[2]);
            float v3 = selu_f(a0[3] + bv[3]);
            u32x2 uu;
            uu.x = ((unsigned)f2bf(v1) << 16) | (unsigned)f2bf(v0);
            uu.y = ((unsigned)f2bf(v3) << 16) | (unsigned)f2bf(v2);
            // byte pos of rows n=w*16+lg*4+r: 64*(w>>1) + 16*lg + 8*(w&1) + 2r
            char* ob = (char*)&zA[(L & 1) ^ 1][0];
            *(u32x2*)(ob + m15 * OZS + 64 * (w >> 1) + 16 * lg + 8 * (w & 1)) = uu;
        } else if (m15 < 4) {
            f32x4 kv;
#pragma unroll
            for (int r = 0; r < 4; ++r) kv[r] = a0[r] + bv[r];
            *(f32x4*)(&k4[m15 * 264 + w * 16 + lg * 4]) = kv;
        }
    }
}

// ---------------- dopri5: 256 blocks (GE=4), 1024 threads, 16 waves -------
__global__ __launch_bounds__(1024, 4) void ode_kernel(
    const float* __restrict__ y0_buf, const float* __restrict__ times,
    const float* __restrict__ doses, const unsigned* __restrict__ WPK,
    const float* __restrict__ ob1, const float* __restrict__ ob2,
    const float* __restrict__ ob3, const float* __restrict__ ob4,
    const float* __restrict__ meta, const float* __restrict__ fcW,
    const float* __restrict__ fcb, float* __restrict__ out) {
    __shared__ unsigned w1lds[32768];              // W1 frags, 128 KiB
    __shared__ short zA[2][16 * OZS / 2];          // ping-pong activations
    __shared__ float bias_lds[4][HD];              // 4 KiB
    __shared__ float k_lds4[4 * 264 + 16];         // padded rows, f32
    __shared__ float flg[4];

    const int tid  = threadIdx.x;
    const int lane = tid & 63;
    const int w    = tid >> 6;             // wave 0..15 == n-tile
    const int we   = w & 3;                // elem this wave mirrors/owns
    const bool owner = (w < 4);
    const int m15  = lane & 15;
    const int lg   = lane >> 4;
    const int b0   = blockIdx.x * GE;
    const int bidx = b0 + we;
    const int d0   = lane * 4;

    // ---- stage W1 frags into LDS (coalesced, once) ----
#pragma unroll
    for (int c = 0; c < 8; ++c) {
        int idx = c * 4096 + tid * 4;
        *(u32x4*)&w1lds[idx] = *(const u32x4*)(WPK + idx);
    }
    // ---- bias table ----
    if (tid < 256) { bias_lds[0][tid] = ob1[tid]; bias_lds[1][tid] = ob2[tid]; }
    else if (tid < 512) { int t = tid - 256; bias_lds[2][t] = ob3[t]; bias_lds[3][t] = ob4[t]; }
    // ---- zero both zA buffers (pads + rows 4-15 stay zero forever) ----
    for (int zi = tid; zi < 2 * 16 * (OZS / 4); zi += 1024)
        ((unsigned*)zA)[zi] = 0u;

    const int sbyte = we * OZS + pperm(d0) * 2;
    char* z0 = (char*)&zA[0][0];

    float y[4];
    {
        const float4 yv = *(const float4*)(y0_buf + bidx * HD + d0);
        y[0] = yv.x; y[1] = yv.y; y[2] = yv.z; y[3] = yv.w;
    }
    __syncthreads();   // staging visible

#define STAGE4(V0, V1, V2, V3)                                              \
    if (owner) {                                                            \
        u32x2 uu;                                                           \
        uu.x = ((unsigned)f2bf(V1) << 16) | (unsigned)f2bf(V0);             \
        uu.y = ((unsigned)f2bf(V3) << 16) | (unsigned)f2bf(V2);             \
        *(u32x2*)(z0 + sbyte) = uu;                                         \
    }

#define EVAL_READ(KV)                                                       \
    eval_mlp16(w1lds, WPK, bias_lds, zA, k_lds4, lane, w, m15, lg);         \
    __syncthreads();                                                        \
    {                                                                       \
        f32x4 kv = *(const f32x4*)(&k_lds4[we * 264 + d0]);                 \
        KV[0] = kv[0]; KV[1] = kv[1]; KV[2] = kv[2]; KV[3] = kv[3];         \
    }

    for (int j = 0; j < 4; ++j) {
        const float tt0 = times[(j * BATCH + bidx) * 2 + 0];
        const float t1  = times[(j * BATCH + bidx) * 2 + 1];
        const float ds  = doses[j * BATCH + bidx];
        const bool act0 = tt0 < t1;
        float ysv[4];
#pragma unroll
        for (int i = 0; i < 4; ++i) { ysv[i] = y[i]; y[i] += ds; }
        float t_s  = tt0;
        float dt_s = fmaxf(t1 - tt0, 1e-6f) * 0.1f;

        if (owner && lane == 0) flg[we] = act0 ? 1.f : 0.f;
        __syncthreads();
        bool anyact = (flg[0] + flg[1] + flg[2] + flg[3]) > 0.f;

        float k1[4], k2[4], k3[4], k4a[4], k5[4], k6[4], k7[4], y5[4], zt[4];
        if (anyact) {
            STAGE4(y[0], y[1], y[2], y[3]);
            EVAL_READ(k1);   // FSAL seed
        }

        for (int step = 0; step < 32 && anyact; ++step) {
            const bool act = t_s < t1;
            // NaN-propagating clip (matches jnp semantics)
            float d = dt_s;
            if (d < 0.f) d = 0.f;
            float rem = t1 - t_s;
            if (rem < 0.f) rem = 0.f;
            if (d > rem) d = rem;

#pragma unroll
            for (int i = 0; i < 4; ++i) zt[i] = y[i] + d * (A21f * k1[i]);
            STAGE4(zt[0], zt[1], zt[2], zt[3]);
            EVAL_READ(k2);
#pragma unroll
            for (int i = 0; i < 4; ++i) zt[i] = y[i] + d * (A31f * k1[i] + A32f * k2[i]);
            STAGE4(zt[0], zt[1], zt[2], zt[3]);
            EVAL_READ(k3);
#pragma unroll
            for (int i = 0; i < 4; ++i) zt[i] = y[i] + d * (A41f * k1[i] + A42f * k2[i] + A43f * k3[i]);
            STAGE4(zt[0], zt[1], zt[2], zt[3]);
            EVAL_READ(k4a);
#pragma unroll
            for (int i = 0; i < 4; ++i) zt[i] = y[i] + d * (A51f * k1[i] + A52f * k2[i] + A53f * k3[i] + A54f * k4a[i]);
            STAGE4(zt[0], zt[1], zt[2], zt[3]);
            EVAL_READ(k5);
#pragma unroll
            for (int i = 0; i < 4; ++i) zt[i] = y[i] + d * (A61f * k1[i] + A62f * k2[i] + A63f * k3[i] + A64f * k4a[i] + A65f * k5[i]);
            STAGE4(zt[0], zt[1], zt[2], zt[3]);
            EVAL_READ(k6);
#pragma unroll
            for (int i = 0; i < 4; ++i)
                y5[i] = y[i] + d * (BC0f * k1[i] + BC2f * k3[i] + BC3f * k4a[i] + BC4f * k5[i] + BC5f * k6[i]);
            STAGE4(y5[0], y5[1], y5[2], y5[3]);
            EVAL_READ(k7);

            float s = 0.f;
#pragma unroll
            for (int i = 0; i < 4; ++i) {
                float err = d * (EC0f * k1[i] + EC2f * k3[i] + EC3f * k4a[i] + EC4f * k5[i] + EC5f * k6[i] + EC6f * k7[i]);
                float sc = 1e-6f + 1e-3f * fmaxf(fabsf(y[i]), fabsf(y5[i]));
                float r = err / sc;
                s = fmaf(r, r, s);
            }
#pragma unroll
            for (int off = 32; off; off >>= 1) s += __shfl_xor(s, off, 64);
            const float en = sqrtf(s * (1.0f / HD));
            const bool accg = (en <= 1.0f) && act;
            if (accg) {
#pragma unroll
                for (int i = 0; i < 4; ++i) { y[i] = y5[i]; k1[i] = k7[i]; }  // FSAL
                t_s = t_s + d;
            }
            float fac = 0.9f * powf(en + 1e-10f, -0.2f);
            if (fac < 0.2f) fac = 0.2f;
            if (fac > 10.f) fac = 10.f;
            if (act) dt_s = fmaxf(d, 1e-8f) * fac;

            if (owner && lane == 0) flg[we] = (t_s < t1) ? 1.f : 0.f;
            __syncthreads();
            anyact = (flg[0] + flg[1] + flg[2] + flg[3]) > 0.f;
        }
#pragma unroll
        for (int i = 0; i < 4; ++i) y[i] = act0 ? y[i] : ysv[i];
    }

    // final FC: out[b] = y . fcW[0:256] + meta . fcW[256:260] + fcb
    float part = 0.f;
#pragma unroll
    for (int i = 0; i < 4; ++i) part = fmaf(y[i], fcW[d0 + i], part);
#pragma unroll
    for (int off = 32; off; off >>= 1) part += __shfl_xor(part, off, 64);
    if (owner && lane == 0) {
        float v = part + fcb[0];
#pragma unroll
        for (int m = 0; m < MMETA; ++m) v += meta[bidx * MMETA + m] * fcW[HD + m];
        out[bidx] = v;
    }
#undef STAGE4
#undef EVAL_READ
}

extern "C" void kernel_launch(void* const* d_in, const int* in_sizes, int n_in,
                              void* d_out, int out_size, void* d_ws, size_t ws_size,
                              hipStream_t stream) {
    const float* x     = (const float*)d_in[0];
    const float* meta  = (const float*)d_in[1];
    const float* eps   = (const float*)d_in[2];
    const float* times = (const float*)d_in[3];
    const float* doses = (const float*)d_in[4];
    const float* Wih   = (const float*)d_in[5];
    const float* Whh   = (const float*)d_in[6];
    const float* bih   = (const float*)d_in[7];
    const float* bhh   = (const float*)d_in[8];
    const float* eW1   = (const float*)d_in[9];
    const float* eb1   = (const float*)d_in[10];
    const float* eW2   = (const float*)d_in[11];
    const float* eb2   = (const float*)d_in[12];
    const float* oW1   = (const float*)d_in[13];
    const float* ob1   = (const float*)d_in[14];
    const float* oW2   = (const float*)d_in[15];
    const float* ob2   = (const float*)d_in[16];
    const float* oW3   = (const float*)d_in[17];
    const float* ob3   = (const float*)d_in[18];
    const float* oW4   = (const float*)d_in[19];
    const float* ob4   = (const float*)d_in[20];
    const float* fcW   = (const float*)d_in[21];
    const float* fcb   = (const float*)d_in[22];

    float* ws = (float*)d_ws;
    unsigned* WihF = (unsigned*)ws;               // u32 [48*256]         12288
    unsigned* WhhF = (unsigned*)(ws + 12288);     // u32 [48*8*256]       98304
    float*    eW1T = ws + 110592;                 // f32 [256][256]       65536
    float*    eW2T = ws + 176128;                 // f32 [256][512]       131072
    unsigned* oWPK = (unsigned*)(ws + 307200);    // u32 [4][16*8*256]    131072
    float*    hbuf = ws + 438272;                 // f32 [1024][256]      262144
    float*    y0b  = hbuf + 262144;               // f32 [1024][256]      262144

    pack_wih<<<12, 256, 0, stream>>>(Wih, WihF);
    pack_mfma_w<<<96, 256, 0, stream>>>(Whh, WhhF);
    transpose_kernel<<<dim3(1, 256), 256, 0, stream>>>(eW1, eW1T, 256, 256);
    transpose_kernel<<<dim3(1, 512), 256, 0, stream>>>(eW2, eW2T, 512, 256);
    pack_mfma_w<<<32, 256, 0, stream>>>(oW1, oWPK);
    pack_mfma_w<<<32, 256, 0, stream>>>(oW2, oWPK + 32768);
    pack_mfma_w<<<32, 256, 0, stream>>>(oW3, oWPK + 65536);
    pack_mfma_w<<<32, 256, 0, stream>>>(oW4, oWPK + 98304);

    gru_kernel<<<BATCH / 4, 1024, 0, stream>>>(x, meta, WihF, WhhF, bih, bhh, hbuf);
    enc_kernel<<<BATCH / 8, 256, 0, stream>>>(hbuf, eps, eW1T, eb1, eW2T, eb2, y0b);
    ode_kernel<<<NBLK, 1024, 0, stream>>>(y0b, times, doses, oWPK, ob1, ob2, ob3, ob4,
                                          meta, fcW, fcb, (float*)d_out);
}

// Round 11
// 1486.483 us; speedup vs baseline: 1.2767x; 1.2767x over previous
//
#include <hip/hip_runtime.h>
#include <math.h>

#define HD 256
#define BATCH 1024
#define NSTEPS 64
#define DIN 4
#define MMETA 4
#define GE 4
#define NBLK (BATCH / GE)

typedef short bf16x8 __attribute__((ext_vector_type(8)));
typedef float f32x4 __attribute__((ext_vector_type(4)));
typedef unsigned u32x2 __attribute__((ext_vector_type(2)));
typedef unsigned u32x4 __attribute__((ext_vector_type(4)));

#define F(x) ((float)(x))
#define A21f F(0.2)
#define A31f F(3.0/40.0)
#define A32f F(9.0/40.0)
#define A41f F(44.0/45.0)
#define A42f F(-56.0/15.0)
#define A43f F(32.0/9.0)
#define A51f F(19372.0/6561.0)
#define A52f F(-25360.0/2187.0)
#define A53f F(64448.0/6561.0)
#define A54f F(-212.0/729.0)
#define A61f F(9017.0/3168.0)
#define A62f F(-355.0/33.0)
#define A63f F(46732.0/5247.0)
#define A64f F(49.0/176.0)
#define A65f F(-5103.0/18656.0)
#define BC0f F(35.0/384.0)
#define BC2f F(500.0/1113.0)
#define BC3f F(125.0/192.0)
#define BC4f F(-2187.0/6784.0)
#define BC5f F(11.0/84.0)
#define EC0f F(35.0/384.0 - 5179.0/57600.0)
#define EC2f F(500.0/1113.0 - 7571.0/16695.0)
#define EC3f F(125.0/192.0 - 393.0/640.0)
#define EC4f F(-2187.0/6784.0 + 92097.0/339200.0)
#define EC5f F(11.0/84.0 - 187.0/2100.0)
#define EC6f F(-1.0/40.0)

#define SELU_SCALE 1.0507009873554805f
#define SELU_SA    1.7580993408473766f   // scale*alpha

__device__ __forceinline__ unsigned short f2bf(float f) {
    unsigned u = __float_as_uint(f);
    return (unsigned short)((u + 0x7fffu + ((u >> 16) & 1u)) >> 16);
}

__device__ __forceinline__ float selu_f(float v) {
    return v > 0.f ? SELU_SCALE * v : fmaf(SELU_SA, __expf(v), -SELU_SA);
}

// Activation tile layout ("frag-major"): element (m, k) lives at byte
//   ks*1024 + lg*256 + m*16 + j*2,
// where k = ks*32 + (j>>2)*16 + lg*4 + (j&3)  (ks=k>>5, lg=(k>>2)&3,
// j=((k>>4)&1)*4+(k&3)).  Then the MFMA A-fragment read for (ks, lane) is at
// byte ks*1024 + lane*16 -> CONTIGUOUS across the wave (bank-conflict-free),
// and the D^T epilogue write is one u32x4 at w*1024 + lane*16 (contiguous).

// ---------------- generic transpose: in[R][C] -> out[C][R] ----------------
__global__ void transpose_kernel(const float* __restrict__ in, float* __restrict__ out,
                                 int R, int C) {
    int c = blockIdx.x * 256 + threadIdx.x;
    int r = blockIdx.y;
    if (c < C) out[c * R + r] = in[r * C + c];
}

// ---- pack W[NT*16][256] f32 into per-lane MFMA fragments -----------------
__global__ void pack_mfma_w(const float* __restrict__ W, unsigned* __restrict__ out) {
    int t = blockIdx.x * 256 + threadIdx.x;
    int lane = t & 63, ks = (t >> 6) & 7, nt = t >> 9;
    int n = nt * 16 + (lane & 15), lg = lane >> 4;
    const float* wr = W + n * HD;
    u32x4 v;
#pragma unroll
    for (int r = 0; r < 4; ++r) {
        int j0 = 2 * r, j1 = 2 * r + 1;
        int k0 = ks * 32 + ((j0 >> 2) << 4) + lg * 4 + (j0 & 3);
        int k1 = ks * 32 + ((j1 >> 2) << 4) + lg * 4 + (j1 & 3);
        v[r] = ((unsigned)f2bf(wr[k1]) << 16) | (unsigned)f2bf(wr[k0]);
    }
    *(u32x4*)(out + t * 4) = v;
}

// ---- pack Wih[768][8] into k=0..7-only fragments (48 nt, 1 ks tile) ------
__global__ void pack_wih(const float* __restrict__ W, unsigned* __restrict__ out) {
    int t = blockIdx.x * 256 + threadIdx.x;
    int lane = t & 63, nt = t >> 6;
    int n = nt * 16 + (lane & 15), lg = lane >> 4;
    u32x4 v;
#pragma unroll
    for (int r = 0; r < 4; ++r) {
        int j0 = 2 * r, j1 = 2 * r + 1;
        int k0 = ((j0 >> 2) << 4) + lg * 4 + (j0 & 3);
        int k1 = ((j1 >> 2) << 4) + lg * 4 + (j1 & 3);
        unsigned a = (k0 < 8) ? (unsigned)f2bf(W[n * 8 + k0]) : 0u;
        unsigned b = (k1 < 8) ? (unsigned)f2bf(W[n * 8 + k1]) : 0u;
        v[r] = (b << 16) | a;
    }
    *(u32x4*)(out + t * 4) = v;
}

// ---------------- GRU via MFMA: 256 blocks (G=4), 512 threads -------------
__global__ __launch_bounds__(512, 2) void gru_kernel(
    const float* __restrict__ x, const float* __restrict__ meta,
    const unsigned* __restrict__ WihF, const unsigned* __restrict__ WhhF,
    const float* __restrict__ bih, const float* __restrict__ bhh,
    float* __restrict__ h_out) {
    __shared__ short zB[9 * 512];       // frag-major, 9 ks-tiles (h + xm), 9216 B
    __shared__ float ghs[768][4];
    __shared__ float ghx[256][4];
    __shared__ float bsum[512], binn[256], bhn[256];

    const int tid  = threadIdx.x;
    const int lane = tid & 63;
    const int w    = tid >> 6;          // wave 0..7
    const int m15  = lane & 15;
    const int lg   = lane >> 4;
    const int b0   = blockIdx.x * 4;

    if (tid < 512) bsum[tid] = bih[tid] + bhh[tid];
    if (tid < 256) { binn[tid] = bih[512 + tid]; bhn[tid] = bhh[512 + tid]; }
    for (int i = tid; i < 9 * 256; i += 512) ((unsigned*)zB)[i] = 0u;

    // byte position (minus m*16) of h element k=tid in frag-major layout
    const int hpb = (tid >> 5) * 1024 + ((tid >> 2) & 3) * 256 +
                    ((((tid >> 4) & 1) * 4 + (tid & 3)) * 2);

    float h_own[4] = {0.f, 0.f, 0.f, 0.f};
    __syncthreads();

    // stage xm for step 0: input c at k=256+c -> byte 8192 + (c>>2)*256 + m*16 + (c&3)*2
    if (tid < 32) {
        int c = tid & 7, m = tid >> 3;
        float v = (c < 4) ? x[((b0 + m) * NSTEPS + 0) * DIN + c]
                          : meta[(b0 + m) * MMETA + (c - 4)];
        *(short*)((char*)zB + 8192 + (c >> 2) * 256 + m * 16 + (c & 3) * 2) = (short)f2bf(v);
    }

    for (int n = 0; n < NSTEPS; ++n) {
        __syncthreads();                // barrier A: zB (h + xm) ready
        bf16x8 zf[9];
#pragma unroll
        for (int ks = 0; ks < 9; ++ks)
            zf[ks] = *(const bf16x8*)((const char*)zB + ks * 1024 + lane * 16);
#pragma unroll
        for (int jn = 0; jn < 6; ++jn) {
            const int nt = w * 6 + jn;
            const unsigned* bp = WhhF + (nt * 8) * 256 + lane * 4;
            f32x4 acc = {0.f, 0.f, 0.f, 0.f};
#pragma unroll
            for (int ks = 0; ks < 8; ++ks) {
                bf16x8 wf = *(const bf16x8*)(bp + ks * 256);
                acc = __builtin_amdgcn_mfma_f32_16x16x32_bf16(wf, zf[ks], acc, 0, 0, 0);
            }
            bf16x8 wih = *(const bf16x8*)(WihF + nt * 256 + lane * 4);
            if (nt < 32) {
                acc = __builtin_amdgcn_mfma_f32_16x16x32_bf16(wih, zf[8], acc, 0, 0, 0);
                if (m15 < 4) {
#pragma unroll
                    for (int r = 0; r < 4; ++r) ghs[nt * 16 + lg * 4 + r][m15] = acc[r];
                }
            } else {
                f32x4 ax = {0.f, 0.f, 0.f, 0.f};
                ax = __builtin_amdgcn_mfma_f32_16x16x32_bf16(wih, zf[8], ax, 0, 0, 0);
                if (m15 < 4) {
#pragma unroll
                    for (int r = 0; r < 4; ++r) {
                        int row = nt * 16 + lg * 4 + r;
                        ghs[row][m15] = acc[r];
                        ghx[row - 512][m15] = ax[r];
                    }
                }
            }
        }
        __syncthreads();                // barrier B: gh ready; zB reads done
        if (tid < 256) {
            f32x4 s0 = *(const f32x4*)(&ghs[tid][0]);
            f32x4 s1 = *(const f32x4*)(&ghs[tid + 256][0]);
            f32x4 hn = *(const f32x4*)(&ghs[tid + 512][0]);
            f32x4 in = *(const f32x4*)(&ghx[tid][0]);
            float bs0 = bsum[tid], bs1 = bsum[tid + 256];
            float bi2 = binn[tid], bh2 = bhn[tid];
#pragma unroll
            for (int m = 0; m < 4; ++m) {
                float rr = 1.f / (1.f + expf(-(s0[m] + bs0)));
                float zz = 1.f / (1.f + expf(-(s1[m] + bs1)));
                float nn = tanhf((in[m] + bi2) + rr * (hn[m] + bh2));
                h_own[m] = (1.f - zz) * nn + zz * h_own[m];
                *(short*)((char*)zB + hpb + m * 16) = (short)f2bf(h_own[m]);
            }
        }
        if (tid < 32 && n + 1 < NSTEPS) {
            int c = tid & 7, m = tid >> 3;
            float v = (c < 4) ? x[((b0 + m) * NSTEPS + (n + 1)) * DIN + c]
                              : meta[(b0 + m) * MMETA + (c - 4)];
            *(short*)((char*)zB + 8192 + (c >> 2) * 256 + m * 16 + (c & 3) * 2) = (short)f2bf(v);
        }
    }
    if (tid < 256) {
#pragma unroll
        for (int m = 0; m < 4; ++m) h_out[(b0 + m) * HD + tid] = h_own[m];
    }
}

// ---------------- encoder + reparameterization (G=8, 128 blocks) ----------
__global__ __launch_bounds__(256) void enc_kernel(
    const float* __restrict__ h_buf, const float* __restrict__ eps,
    const float* __restrict__ W1T, const float* __restrict__ b1,
    const float* __restrict__ W2T, const float* __restrict__ b2,
    float* __restrict__ y0_buf) {
    __shared__ float zsh[HD][8];
    const int tid = threadIdx.x;
    const int b0 = blockIdx.x * 8;
#pragma unroll
    for (int g = 0; g < 8; ++g) zsh[tid][g] = h_buf[(b0 + g) * HD + tid];
    __syncthreads();
    float acc[8];
    {
        float bb = b1[tid];
#pragma unroll
        for (int g = 0; g < 8; ++g) acc[g] = bb;
        for (int k = 0; k < HD; k += 4) {
#pragma unroll
            for (int u = 0; u < 4; ++u) {
                float w = W1T[(k + u) * HD + tid];
                const float4 za = *(const float4*)(&zsh[k + u][0]);
                const float4 zb = *(const float4*)(&zsh[k + u][4]);
                acc[0] = fmaf(w, za.x, acc[0]); acc[1] = fmaf(w, za.y, acc[1]);
                acc[2] = fmaf(w, za.z, acc[2]); acc[3] = fmaf(w, za.w, acc[3]);
                acc[4] = fmaf(w, zb.x, acc[4]); acc[5] = fmaf(w, zb.y, acc[5]);
                acc[6] = fmaf(w, zb.z, acc[6]); acc[7] = fmaf(w, zb.w, acc[7]);
            }
        }
    }
    __syncthreads();
#pragma unroll
    for (int g = 0; g < 8; ++g) zsh[tid][g] = fmaxf(acc[g], 0.f);
    __syncthreads();
    float am[8], as[8];
    {
        float bm = b2[tid], bs = b2[tid + HD];
#pragma unroll
        for (int g = 0; g < 8; ++g) { am[g] = bm; as[g] = bs; }
        for (int k = 0; k < HD; k += 4) {
#pragma unroll
            for (int u = 0; u < 4; ++u) {
                float wm = W2T[(k + u) * 512 + tid];
                float ws2 = W2T[(k + u) * 512 + HD + tid];
                const float4 za = *(const float4*)(&zsh[k + u][0]);
                const float4 zb = *(const float4*)(&zsh[k + u][4]);
                am[0] = fmaf(wm, za.x, am[0]); am[1] = fmaf(wm, za.y, am[1]);
                am[2] = fmaf(wm, za.z, am[2]); am[3] = fmaf(wm, za.w, am[3]);
                am[4] = fmaf(wm, zb.x, am[4]); am[5] = fmaf(wm, zb.y, am[5]);
                am[6] = fmaf(wm, zb.z, am[6]); am[7] = fmaf(wm, zb.w, am[7]);
                as[0] = fmaf(ws2, za.x, as[0]); as[1] = fmaf(ws2, za.y, as[1]);
                as[2] = fmaf(ws2, za.z, as[2]); as[3] = fmaf(ws2, za.w, as[3]);
                as[4] = fmaf(ws2, zb.x, as[4]); as[5] = fmaf(ws2, zb.y, as[5]);
                as[6] = fmaf(ws2, zb.z, as[6]); as[7] = fmaf(ws2, zb.w, as[7]);
            }
        }
    }
#pragma unroll
    for (int g = 0; g < 8; ++g)
        y0_buf[(b0 + g) * HD + tid] = eps[(b0 + g) * HD + tid] * as[g] + am[g];
}

// ---------- MFMA 4-layer MLP: W1 from LDS, W2-W4 streamed from L2 ---------
// Frag-major zA: all LDS reads/writes contiguous per wave.
__device__ __forceinline__ void eval_mlp8(
    const unsigned* __restrict__ w1l, const unsigned* __restrict__ WPK,
    const float (*bias)[HD], short (*zA)[8 * 512], float* __restrict__ k4,
    int lane, int w, int m15, int lg) {
    const int nt0 = 2 * w, nt1 = 2 * w + 1;
#pragma unroll
    for (int L = 0; L < 4; ++L) {
        __syncthreads();   // staged y' / previous epilogue visible; WAR safe
        const char* ibp = (const char*)&zA[L & 1][0];
        bf16x8 zf[8];
#pragma unroll
        for (int ks = 0; ks < 8; ++ks)
            zf[ks] = *(const bf16x8*)(ibp + ks * 1024 + lane * 16);
        f32x4 a0 = {0.f, 0.f, 0.f, 0.f}, a1 = {0.f, 0.f, 0.f, 0.f};
#pragma unroll
        for (int ks = 0; ks < 8; ++ks) {
            bf16x8 wf0, wf1;
            if (L == 0) {
                wf0 = *(const bf16x8*)(w1l + (nt0 * 8 + ks) * 256 + lane * 4);
                wf1 = *(const bf16x8*)(w1l + (nt1 * 8 + ks) * 256 + lane * 4);
            } else {
                wf0 = *(const bf16x8*)(WPK + ((L * 16 + nt0) * 8 + ks) * 256 + lane * 4);
                wf1 = *(const bf16x8*)(WPK + ((L * 16 + nt1) * 8 + ks) * 256 + lane * 4);
            }
            a0 = __builtin_amdgcn_mfma_f32_16x16x32_bf16(wf0, zf[ks], a0, 0, 0, 0);
            a1 = __builtin_amdgcn_mfma_f32_16x16x32_bf16(wf1, zf[ks], a1, 0, 0, 0);
        }
        // D^T: lane holds col m=m15, rows n = nt*16 + lg*4 + r.
        // New element byte: n in tile ks_n = w, j = (nt&1)*4 + r, lg_n = lg
        //  -> nt0 pair at w*1024 + lane*16 + 0..7, nt1 pair at +8..15: one u32x4.
        const f32x4 bv0 = *(const f32x4*)(&bias[L][nt0 * 16 + lg * 4]);
        const f32x4 bv1 = *(const f32x4*)(&bias[L][nt1 * 16 + lg * 4]);
        if (L < 3) {
            float v0 = selu_f(a0[0] + bv0[0]);
            float v1 = selu_f(a0[1] + bv0[1]);
            float v2 = selu_f(a0[2] + bv0[2]);
            float v3 = selu_f(a0[3] + bv0[3]);
            float v4 = selu_f(a1[0] + bv1[0]);
            float v5 = selu_f(a1[1] + bv1[1]);
            float v6 = selu_f(a1[2] + bv1[2]);
            float v7 = selu_f(a1[3] + bv1[3]);
            u32x4 uu;
            uu.x = ((unsigned)f2bf(v1) << 16) | (unsigned)f2bf(v0);
            uu.y = ((unsigned)f2bf(v3) << 16) | (unsigned)f2bf(v2);
            uu.z = ((unsigned)f2bf(v5) << 16) | (unsigned)f2bf(v4);
            uu.w = ((unsigned)f2bf(v7) << 16) | (unsigned)f2bf(v6);
            char* ob = (char*)&zA[(L & 1) ^ 1][0];
            *(u32x4*)(ob + w * 1024 + lane * 16) = uu;
        } else if (m15 < 4) {
            f32x4 kv0, kv1;
#pragma unroll
            for (int r = 0; r < 4; ++r) { kv0[r] = a0[r] + bv0[r]; kv1[r] = a1[r] + bv1[r]; }
            *(f32x4*)(&k4[m15 * 264 + nt0 * 16 + lg * 4]) = kv0;
            *(f32x4*)(&k4[m15 * 264 + nt1 * 16 + lg * 4]) = kv1;
        }
    }
}

// ---------------- dopri5: 256 blocks (GE=4), 512 threads, 8 waves ---------
__global__ __launch_bounds__(512, 2) void ode_kernel(
    const float* __restrict__ y0_buf, const float* __restrict__ times,
    const float* __restrict__ doses, const unsigned* __restrict__ WPK,
    const float* __restrict__ ob1, const float* __restrict__ ob2,
    const float* __restrict__ ob3, const float* __restrict__ ob4,
    const float* __restrict__ meta, const float* __restrict__ fcW,
    const float* __restrict__ fcb, float* __restrict__ out) {
    __shared__ unsigned w1lds[32768];        // W1 frags, 128 KiB
    __shared__ short zA[2][8 * 512];         // ping-pong frag-major activations, 2x8 KiB
    __shared__ float bias_lds[4][HD];        // 4 KiB
    __shared__ float k_lds4[4 * 264 + 16];   // padded rows, f32
    __shared__ float flg[4];

    const int tid  = threadIdx.x;
    const int lane = tid & 63;
    const int w    = tid >> 6;             // wave 0..7
    const int we   = w & 3;                // elem this wave mirrors/owns
    const bool owner = (w < 4);
    const int m15  = lane & 15;
    const int lg   = lane >> 4;
    const int b0   = blockIdx.x * GE;
    const int bidx = b0 + we;
    const int d0   = lane * 4;

    // ---- stage W1 frags into LDS (coalesced, once) ----
#pragma unroll
    for (int c = 0; c < 16; ++c) {
        int idx = c * 2048 + tid * 4;
        *(u32x4*)&w1lds[idx] = *(const u32x4*)(WPK + idx);
    }
    // ---- bias table ----
    if (tid < 256) { bias_lds[0][tid] = ob1[tid]; bias_lds[1][tid] = ob2[tid]; }
    else if (tid < 512) { int t = tid - 256; bias_lds[2][t] = ob3[t]; bias_lds[3][t] = ob4[t]; }
    // ---- zero both zA buffers (garbage rows stay finite forever) ----
    for (int zi = tid; zi < 2 * 8 * 256; zi += 512)
        ((unsigned*)zA)[zi] = 0u;

    // stage byte for y'(k=4q..4q+3, m=we), q=lane:
    //   ks=q>>3, lg=q&3, j=((q>>2)&1)*4 + i  -> 8B at:
    const int sbyte = (lane >> 3) * 1024 + (lane & 3) * 256 + we * 16 + ((lane >> 2) & 1) * 8;
    char* z0 = (char*)&zA[0][0];

    float y[4];
    {
        const float4 yv = *(const float4*)(y0_buf + bidx * HD + d0);
        y[0] = yv.x; y[1] = yv.y; y[2] = yv.z; y[3] = yv.w;
    }
    __syncthreads();   // staging visible

#define STAGE4(V0, V1, V2, V3)                                              \
    if (owner) {                                                            \
        u32x2 uu;                                                           \
        uu.x = ((unsigned)f2bf(V1) << 16) | (unsigned)f2bf(V0);             \
        uu.y = ((unsigned)f2bf(V3) << 16) | (unsigned)f2bf(V2);             \
        *(u32x2*)(z0 + sbyte) = uu;                                         \
    }

#define EVAL_READ(KV)                                                       \
    eval_mlp8(w1lds, WPK, bias_lds, zA, k_lds4, lane, w, m15, lg);          \
    __syncthreads();                                                        \
    {                                                                       \
        f32x4 kv = *(const f32x4*)(&k_lds4[we * 264 + d0]);                 \
        KV[0] = kv[0]; KV[1] = kv[1]; KV[2] = kv[2]; KV[3] = kv[3];         \
    }

    for (int j = 0; j < 4; ++j) {
        const float tt0 = times[(j * BATCH + bidx) * 2 + 0];
        const float t1  = times[(j * BATCH + bidx) * 2 + 1];
        const float ds  = doses[j * BATCH + bidx];
        const bool act0 = tt0 < t1;
        float ysv[4];
#pragma unroll
        for (int i = 0; i < 4; ++i) { ysv[i] = y[i]; y[i] += ds; }
        float t_s  = tt0;
        float dt_s = fmaxf(t1 - tt0, 1e-6f) * 0.1f;

        if (owner && lane == 0) flg[we] = act0 ? 1.f : 0.f;
        __syncthreads();
        bool anyact = (flg[0] + flg[1] + flg[2] + flg[3]) > 0.f;

        float k1[4], k2[4], k3[4], k4a[4], k5[4], k6[4], k7[4], y5[4], zt[4];
        if (anyact) {
            STAGE4(y[0], y[1], y[2], y[3]);
            EVAL_READ(k1);   // FSAL seed
        }

        for (int step = 0; step < 32 && anyact; ++step) {
            const bool act = t_s < t1;
            // NaN-propagating clip (matches jnp semantics)
            float d = dt_s;
            if (d < 0.f) d = 0.f;
            float rem = t1 - t_s;
            if (rem < 0.f) rem = 0.f;
            if (d > rem) d = rem;

#pragma unroll
            for (int i = 0; i < 4; ++i) zt[i] = y[i] + d * (A21f * k1[i]);
            STAGE4(zt[0], zt[1], zt[2], zt[3]);
            EVAL_READ(k2);
#pragma unroll
            for (int i = 0; i < 4; ++i) zt[i] = y[i] + d * (A31f * k1[i] + A32f * k2[i]);
            STAGE4(zt[0], zt[1], zt[2], zt[3]);
            EVAL_READ(k3);
#pragma unroll
            for (int i = 0; i < 4; ++i) zt[i] = y[i] + d * (A41f * k1[i] + A42f * k2[i] + A43f * k3[i]);
            STAGE4(zt[0], zt[1], zt[2], zt[3]);
            EVAL_READ(k4a);
#pragma unroll
            for (int i = 0; i < 4; ++i) zt[i] = y[i] + d * (A51f * k1[i] + A52f * k2[i] + A53f * k3[i] + A54f * k4a[i]);
            STAGE4(zt[0], zt[1], zt[2], zt[3]);
            EVAL_READ(k5);
#pragma unroll
            for (int i = 0; i < 4; ++i) zt[i] = y[i] + d * (A61f * k1[i] + A62f * k2[i] + A63f * k3[i] + A64f * k4a[i] + A65f * k5[i]);
            STAGE4(zt[0], zt[1], zt[2], zt[3]);
            EVAL_READ(k6);
#pragma unroll
            for (int i = 0; i < 4; ++i)
                y5[i] = y[i] + d * (BC0f * k1[i] + BC2f * k3[i] + BC3f * k4a[i] + BC4f * k5[i] + BC5f * k6[i]);
            STAGE4(y5[0], y5[1], y5[2], y5[3]);
            EVAL_READ(k7);

            float s = 0.f;
#pragma unroll
            for (int i = 0; i < 4; ++i) {
                float err = d * (EC0f * k1[i] + EC2f * k3[i] + EC3f * k4a[i] + EC4f * k5[i] + EC5f * k6[i] + EC6f * k7[i]);
                float sc = 1e-6f + 1e-3f * fmaxf(fabsf(y[i]), fabsf(y5[i]));
                float r = err / sc;
                s = fmaf(r, r, s);
            }
#pragma unroll
            for (int off = 32; off; off >>= 1) s += __shfl_xor(s, off, 64);
            const float en = sqrtf(s * (1.0f / HD));
            const bool accg = (en <= 1.0f) && act;
            if (accg) {
#pragma unroll
                for (int i = 0; i < 4; ++i) { y[i] = y5[i]; k1[i] = k7[i]; }  // FSAL
                t_s = t_s + d;
            }
            float fac = 0.9f * powf(en + 1e-10f, -0.2f);
            if (fac < 0.2f) fac = 0.2f;
            if (fac > 10.f) fac = 10.f;
            if (act) dt_s = fmaxf(d, 1e-8f) * fac;

            if (owner && lane == 0) flg[we] = (t_s < t1) ? 1.f : 0.f;
            __syncthreads();
            anyact = (flg[0] + flg[1] + flg[2] + flg[3]) > 0.f;
        }
#pragma unroll
        for (int i = 0; i < 4; ++i) y[i] = act0 ? y[i] : ysv[i];
    }

    // final FC: out[b] = y . fcW[0:256] + meta . fcW[256:260] + fcb
    float part = 0.f;
#pragma unroll
    for (int i = 0; i < 4; ++i) part = fmaf(y[i], fcW[d0 + i], part);
#pragma unroll
    for (int off = 32; off; off >>= 1) part += __shfl_xor(part, off, 64);
    if (owner && lane == 0) {
        float v = part + fcb[0];
#pragma unroll
        for (int m = 0; m < MMETA; ++m) v += meta[bidx * MMETA + m] * fcW[HD + m];
        out[bidx] = v;
    }
#undef STAGE4
#undef EVAL_READ
}

extern "C" void kernel_launch(void* const* d_in, const int* in_sizes, int n_in,
                              void* d_out, int out_size, void* d_ws, size_t ws_size,
                              hipStream_t stream) {
    const float* x     = (const float*)d_in[0];
    const float* meta  = (const float*)d_in[1];
    const float* eps   = (const float*)d_in[2];
    const float* times = (const float*)d_in[3];
    const float* doses = (const float*)d_in[4];
    const float* Wih   = (const float*)d_in[5];
    const float* Whh   = (const float*)d_in[6];
    const float* bih   = (const float*)d_in[7];
    const float* bhh   = (const float*)d_in[8];
    const float* eW1   = (const float*)d_in[9];
    const float* eb1   = (const float*)d_in[10];
    const float* eW2   = (const float*)d_in[11];
    const float* eb2   = (const float*)d_in[12];
    const float* oW1   = (const float*)d_in[13];
    const float* ob1   = (const float*)d_in[14];
    const float* oW2   = (const float*)d_in[15];
    const float* ob2   = (const float*)d_in[16];
    const float* oW3   = (const float*)d_in[17];
    const float* ob3   = (const float*)d_in[18];
    const float* oW4   = (const float*)d_in[19];
    const float* ob4   = (const float*)d_in[20];
    const float* fcW   = (const float*)d_in[21];
    const float* fcb   = (const float*)d_in[22];

    float* ws = (float*)d_ws;
    unsigned* WihF = (unsigned*)ws;               // u32 [48*256]         12288
    unsigned* WhhF = (unsigned*)(ws + 12288);     // u32 [48*8*256]       98304
    float*    eW1T = ws + 110592;                 // f32 [256][256]       65536
    float*    eW2T = ws + 176128;                 // f32 [256][512]       131072
    unsigned* oWPK = (unsigned*)(ws + 307200);    // u32 [4][16*8*256]    131072
    float*    hbuf = ws + 438272;                 // f32 [1024][256]      262144
    float*    y0b  = hbuf + 262144;               // f32 [1024][256]      262144

    pack_wih<<<12, 256, 0, stream>>>(Wih, WihF);
    pack_mfma_w<<<96, 256, 0, stream>>>(Whh, WhhF);
    transpose_kernel<<<dim3(1, 256), 256, 0, stream>>>(eW1, eW1T, 256, 256);
    transpose_kernel<<<dim3(1, 512), 256, 0, stream>>>(eW2, eW2T, 512, 256);
    pack_mfma_w<<<32, 256, 0, stream>>>(oW1, oWPK);
    pack_mfma_w<<<32, 256, 0, stream>>>(oW2, oWPK + 32768);
    pack_mfma_w<<<32, 256, 0, stream>>>(oW3, oWPK + 65536);
    pack_mfma_w<<<32, 256, 0, stream>>>(oW4, oWPK + 98304);

    gru_kernel<<<BATCH / 4, 512, 0, stream>>>(x, meta, WihF, WhhF, bih, bhh, hbuf);
    enc_kernel<<<BATCH / 8, 256, 0, stream>>>(hbuf, eps, eW1T, eb1, eW2T, eb2, y0b);
    ode_kernel<<<NBLK, 512, 0, stream>>>(y0b, times, doses, oWPK, ob1, ob2, ob3, ob4,
                                         meta, fcW, fcb, (float*)d_out);
}

// Round 12
// 1331.153 us; speedup vs baseline: 1.4256x; 1.1167x over previous
//
#include <hip/hip_runtime.h>
#include <math.h>

#define HD 256
#define BATCH 1024
#define NSTEPS 64
#define DIN 4
#define MMETA 4
#define GE 4
#define NBLK (BATCH / GE)

typedef short bf16x8 __attribute__((ext_vector_type(8)));
typedef float f32x4 __attribute__((ext_vector_type(4)));
typedef unsigned u32x2 __attribute__((ext_vector_type(2)));
typedef unsigned u32x4 __attribute__((ext_vector_type(4)));

#define F(x) ((float)(x))
#define A21f F(0.2)
#define A31f F(3.0/40.0)
#define A32f F(9.0/40.0)
#define A41f F(44.0/45.0)
#define A42f F(-56.0/15.0)
#define A43f F(32.0/9.0)
#define A51f F(19372.0/6561.0)
#define A52f F(-25360.0/2187.0)
#define A53f F(64448.0/6561.0)
#define A54f F(-212.0/729.0)
#define A61f F(9017.0/3168.0)
#define A62f F(-355.0/33.0)
#define A63f F(46732.0/5247.0)
#define A64f F(49.0/176.0)
#define A65f F(-5103.0/18656.0)
#define BC0f F(35.0/384.0)
#define BC2f F(500.0/1113.0)
#define BC3f F(125.0/192.0)
#define BC4f F(-2187.0/6784.0)
#define BC5f F(11.0/84.0)
#define EC0f F(35.0/384.0 - 5179.0/57600.0)
#define EC2f F(500.0/1113.0 - 7571.0/16695.0)
#define EC3f F(125.0/192.0 - 393.0/640.0)
#define EC4f F(-2187.0/6784.0 + 92097.0/339200.0)
#define EC5f F(11.0/84.0 - 187.0/2100.0)
#define EC6f F(-1.0/40.0)

#define SELU_SCALE 1.0507009873554805f
#define SELU_SA    1.7580993408473766f   // scale*alpha

__device__ __forceinline__ unsigned short f2bf(float f) {
    unsigned u = __float_as_uint(f);
    return (unsigned short)((u + 0x7fffu + ((u >> 16) & 1u)) >> 16);
}

__device__ __forceinline__ float selu_f(float v) {
    return v > 0.f ? SELU_SCALE * v : fmaf(SELU_SA, __expf(v), -SELU_SA);
}

// Activation tile layout ("frag-major"): element (m, k) lives at byte
//   ks*1024 + lg*256 + m*16 + j*2,
// where k = ks*32 + (j>>2)*16 + lg*4 + (j&3).  The MFMA A-fragment read for
// (ks, lane) is at byte ks*1024 + lane*16 -> CONTIGUOUS across the wave
// (bank-conflict-free; verified R11: conflicts 64M -> 4.5M), and the D^T
// epilogue write is one u32x4 at w*1024 + lane*16 (contiguous).

// ---------------- generic transpose: in[R][C] -> out[C][R] ----------------
__global__ void transpose_kernel(const float* __restrict__ in, float* __restrict__ out,
                                 int R, int C) {
    int c = blockIdx.x * 256 + threadIdx.x;
    int r = blockIdx.y;
    if (c < C) out[c * R + r] = in[r * C + c];
}

// ---- pack W[NT*16][256] f32 into per-lane MFMA fragments -----------------
__global__ void pack_mfma_w(const float* __restrict__ W, unsigned* __restrict__ out) {
    int t = blockIdx.x * 256 + threadIdx.x;
    int lane = t & 63, ks = (t >> 6) & 7, nt = t >> 9;
    int n = nt * 16 + (lane & 15), lg = lane >> 4;
    const float* wr = W + n * HD;
    u32x4 v;
#pragma unroll
    for (int r = 0; r < 4; ++r) {
        int j0 = 2 * r, j1 = 2 * r + 1;
        int k0 = ks * 32 + ((j0 >> 2) << 4) + lg * 4 + (j0 & 3);
        int k1 = ks * 32 + ((j1 >> 2) << 4) + lg * 4 + (j1 & 3);
        v[r] = ((unsigned)f2bf(wr[k1]) << 16) | (unsigned)f2bf(wr[k0]);
    }
    *(u32x4*)(out + t * 4) = v;
}

// ---- pack Wih[768][8] into k=0..7-only fragments (48 nt, 1 ks tile) ------
__global__ void pack_wih(const float* __restrict__ W, unsigned* __restrict__ out) {
    int t = blockIdx.x * 256 + threadIdx.x;
    int lane = t & 63, nt = t >> 6;
    int n = nt * 16 + (lane & 15), lg = lane >> 4;
    u32x4 v;
#pragma unroll
    for (int r = 0; r < 4; ++r) {
        int j0 = 2 * r, j1 = 2 * r + 1;
        int k0 = ((j0 >> 2) << 4) + lg * 4 + (j0 & 3);
        int k1 = ((j1 >> 2) << 4) + lg * 4 + (j1 & 3);
        unsigned a = (k0 < 8) ? (unsigned)f2bf(W[n * 8 + k0]) : 0u;
        unsigned b = (k1 < 8) ? (unsigned)f2bf(W[n * 8 + k1]) : 0u;
        v[r] = (b << 16) | a;
    }
    *(u32x4*)(out + t * 4) = v;
}

// ---------------- GRU via MFMA: 256 blocks (G=4), 512 threads -------------
__global__ __launch_bounds__(512, 2) void gru_kernel(
    const float* __restrict__ x, const float* __restrict__ meta,
    const unsigned* __restrict__ WihF, const unsigned* __restrict__ WhhF,
    const float* __restrict__ bih, const float* __restrict__ bhh,
    float* __restrict__ h_out) {
    __shared__ short zB[9 * 512];       // frag-major, 9 ks-tiles (h + xm), 9216 B
    __shared__ float ghs[768][4];
    __shared__ float ghx[256][4];
    __shared__ float bsum[512], binn[256], bhn[256];

    const int tid  = threadIdx.x;
    const int lane = tid & 63;
    const int w    = tid >> 6;          // wave 0..7
    const int m15  = lane & 15;
    const int lg   = lane >> 4;
    const int b0   = blockIdx.x * 4;

    if (tid < 512) bsum[tid] = bih[tid] + bhh[tid];
    if (tid < 256) { binn[tid] = bih[512 + tid]; bhn[tid] = bhh[512 + tid]; }
    for (int i = tid; i < 9 * 256; i += 512) ((unsigned*)zB)[i] = 0u;

    // byte position (minus m*16) of h element k=tid in frag-major layout
    const int hpb = (tid >> 5) * 1024 + ((tid >> 2) & 3) * 256 +
                    ((((tid >> 4) & 1) * 4 + (tid & 3)) * 2);

    float h_own[4] = {0.f, 0.f, 0.f, 0.f};
    __syncthreads();

    // stage xm for step 0: input c at k=256+c -> byte 8192 + (c>>2)*256 + m*16 + (c&3)*2
    if (tid < 32) {
        int c = tid & 7, m = tid >> 3;
        float v = (c < 4) ? x[((b0 + m) * NSTEPS + 0) * DIN + c]
                          : meta[(b0 + m) * MMETA + (c - 4)];
        *(short*)((char*)zB + 8192 + (c >> 2) * 256 + m * 16 + (c & 3) * 2) = (short)f2bf(v);
    }

    for (int n = 0; n < NSTEPS; ++n) {
        __syncthreads();                // barrier A: zB (h + xm) ready
        bf16x8 zf[9];
#pragma unroll
        for (int ks = 0; ks < 9; ++ks)
            zf[ks] = *(const bf16x8*)((const char*)zB + ks * 1024 + lane * 16);
#pragma unroll
        for (int jn = 0; jn < 6; ++jn) {
            const int nt = w * 6 + jn;
            const unsigned* bp = WhhF + (nt * 8) * 256 + lane * 4;
            f32x4 acc = {0.f, 0.f, 0.f, 0.f};
#pragma unroll
            for (int ks = 0; ks < 8; ++ks) {
                bf16x8 wf = *(const bf16x8*)(bp + ks * 256);
                acc = __builtin_amdgcn_mfma_f32_16x16x32_bf16(wf, zf[ks], acc, 0, 0, 0);
            }
            bf16x8 wih = *(const bf16x8*)(WihF + nt * 256 + lane * 4);
            if (nt < 32) {
                acc = __builtin_amdgcn_mfma_f32_16x16x32_bf16(wih, zf[8], acc, 0, 0, 0);
                if (m15 < 4) {
#pragma unroll
                    for (int r = 0; r < 4; ++r) ghs[nt * 16 + lg * 4 + r][m15] = acc[r];
                }
            } else {
                f32x4 ax = {0.f, 0.f, 0.f, 0.f};
                ax = __builtin_amdgcn_mfma_f32_16x16x32_bf16(wih, zf[8], ax, 0, 0, 0);
                if (m15 < 4) {
#pragma unroll
                    for (int r = 0; r < 4; ++r) {
                        int row = nt * 16 + lg * 4 + r;
                        ghs[row][m15] = acc[r];
                        ghx[row - 512][m15] = ax[r];
                    }
                }
            }
        }
        __syncthreads();                // barrier B: gh ready; zB reads done
        if (tid < 256) {
            f32x4 s0 = *(const f32x4*)(&ghs[tid][0]);
            f32x4 s1 = *(const f32x4*)(&ghs[tid + 256][0]);
            f32x4 hn = *(const f32x4*)(&ghs[tid + 512][0]);
            f32x4 in = *(const f32x4*)(&ghx[tid][0]);
            float bs0 = bsum[tid], bs1 = bsum[tid + 256];
            float bi2 = binn[tid], bh2 = bhn[tid];
#pragma unroll
            for (int m = 0; m < 4; ++m) {
                float rr = 1.f / (1.f + expf(-(s0[m] + bs0)));
                float zz = 1.f / (1.f + expf(-(s1[m] + bs1)));
                float nn = tanhf((in[m] + bi2) + rr * (hn[m] + bh2));
                h_own[m] = (1.f - zz) * nn + zz * h_own[m];
                *(short*)((char*)zB + hpb + m * 16) = (short)f2bf(h_own[m]);
            }
        }
        if (tid < 32 && n + 1 < NSTEPS) {
            int c = tid & 7, m = tid >> 3;
            float v = (c < 4) ? x[((b0 + m) * NSTEPS + (n + 1)) * DIN + c]
                              : meta[(b0 + m) * MMETA + (c - 4)];
            *(short*)((char*)zB + 8192 + (c >> 2) * 256 + m * 16 + (c & 3) * 2) = (short)f2bf(v);
        }
    }
    if (tid < 256) {
#pragma unroll
        for (int m = 0; m < 4; ++m) h_out[(b0 + m) * HD + tid] = h_own[m];
    }
}

// ---------------- encoder + reparameterization (G=8, 128 blocks) ----------
__global__ __launch_bounds__(256) void enc_kernel(
    const float* __restrict__ h_buf, const float* __restrict__ eps,
    const float* __restrict__ W1T, const float* __restrict__ b1,
    const float* __restrict__ W2T, const float* __restrict__ b2,
    float* __restrict__ y0_buf) {
    __shared__ float zsh[HD][8];
    const int tid = threadIdx.x;
    const int b0 = blockIdx.x * 8;
#pragma unroll
    for (int g = 0; g < 8; ++g) zsh[tid][g] = h_buf[(b0 + g) * HD + tid];
    __syncthreads();
    float acc[8];
    {
        float bb = b1[tid];
#pragma unroll
        for (int g = 0; g < 8; ++g) acc[g] = bb;
        for (int k = 0; k < HD; k += 4) {
#pragma unroll
            for (int u = 0; u < 4; ++u) {
                float w = W1T[(k + u) * HD + tid];
                const float4 za = *(const float4*)(&zsh[k + u][0]);
                const float4 zb = *(const float4*)(&zsh[k + u][4]);
                acc[0] = fmaf(w, za.x, acc[0]); acc[1] = fmaf(w, za.y, acc[1]);
                acc[2] = fmaf(w, za.z, acc[2]); acc[3] = fmaf(w, za.w, acc[3]);
                acc[4] = fmaf(w, zb.x, acc[4]); acc[5] = fmaf(w, zb.y, acc[5]);
                acc[6] = fmaf(w, zb.z, acc[6]); acc[7] = fmaf(w, zb.w, acc[7]);
            }
        }
    }
    __syncthreads();
#pragma unroll
    for (int g = 0; g < 8; ++g) zsh[tid][g] = fmaxf(acc[g], 0.f);
    __syncthreads();
    float am[8], as[8];
    {
        float bm = b2[tid], bs = b2[tid + HD];
#pragma unroll
        for (int g = 0; g < 8; ++g) { am[g] = bm; as[g] = bs; }
        for (int k = 0; k < HD; k += 4) {
#pragma unroll
            for (int u = 0; u < 4; ++u) {
                float wm = W2T[(k + u) * 512 + tid];
                float ws2 = W2T[(k + u) * 512 + HD + tid];
                const float4 za = *(const float4*)(&zsh[k + u][0]);
                const float4 zb = *(const float4*)(&zsh[k + u][4]);
                am[0] = fmaf(wm, za.x, am[0]); am[1] = fmaf(wm, za.y, am[1]);
                am[2] = fmaf(wm, za.z, am[2]); am[3] = fmaf(wm, za.w, am[3]);
                am[4] = fmaf(wm, zb.x, am[4]); am[5] = fmaf(wm, zb.y, am[5]);
                am[6] = fmaf(wm, zb.z, am[6]); am[7] = fmaf(wm, zb.w, am[7]);
                as[0] = fmaf(ws2, za.x, as[0]); as[1] = fmaf(ws2, za.y, as[1]);
                as[2] = fmaf(ws2, za.z, as[2]); as[3] = fmaf(ws2, za.w, as[3]);
                as[4] = fmaf(ws2, zb.x, as[4]); as[5] = fmaf(ws2, zb.y, as[5]);
                as[6] = fmaf(ws2, zb.z, as[6]); as[7] = fmaf(ws2, zb.w, as[7]);
            }
        }
    }
#pragma unroll
    for (int g = 0; g < 8; ++g)
        y0_buf[(b0 + g) * HD + tid] = eps[(b0 + g) * HD + tid] * as[g] + am[g];
}

// ---------- MFMA 4-layer MLP: W1 from LDS, W2-W4 streamed from L2 ---------
// Frag-major zA: all LDS reads/writes contiguous per wave. zf processed in
// two halves of 4 ks-tiles to halve live register pressure.
__device__ __forceinline__ void eval_mlp8(
    const unsigned* __restrict__ w1l, const unsigned* __restrict__ WPK,
    const float (*bias)[HD], short (*zA)[8 * 512], float* __restrict__ k4,
    int lane, int w, int m15, int lg) {
    const int nt0 = 2 * w, nt1 = 2 * w + 1;
#pragma unroll
    for (int L = 0; L < 4; ++L) {
        __syncthreads();   // staged y' / previous epilogue visible; WAR safe
        const char* ibp = (const char*)&zA[L & 1][0];
        const unsigned* wb0 = (L == 0) ? (w1l + (nt0 * 8) * 256 + lane * 4)
                                       : (WPK + ((L * 16 + nt0) * 8) * 256 + lane * 4);
        const unsigned* wb1 = (L == 0) ? (w1l + (nt1 * 8) * 256 + lane * 4)
                                       : (WPK + ((L * 16 + nt1) * 8) * 256 + lane * 4);
        f32x4 a0 = {0.f, 0.f, 0.f, 0.f}, a1 = {0.f, 0.f, 0.f, 0.f};
#pragma unroll
        for (int h = 0; h < 2; ++h) {
            bf16x8 zf[4];
#pragma unroll
            for (int q = 0; q < 4; ++q)
                zf[q] = *(const bf16x8*)(ibp + (h * 4 + q) * 1024 + lane * 16);
#pragma unroll
            for (int q = 0; q < 4; ++q) {
                const int ks = h * 4 + q;
                bf16x8 wf0 = *(const bf16x8*)(wb0 + ks * 256);
                bf16x8 wf1 = *(const bf16x8*)(wb1 + ks * 256);
                a0 = __builtin_amdgcn_mfma_f32_16x16x32_bf16(wf0, zf[q], a0, 0, 0, 0);
                a1 = __builtin_amdgcn_mfma_f32_16x16x32_bf16(wf1, zf[q], a1, 0, 0, 0);
            }
        }
        // D^T: lane holds col m=m15, rows n = nt*16 + lg*4 + r.
        // Frag-major target: nt0 pair -> w*1024 + lane*16 + 0..7, nt1 -> +8..15.
        const f32x4 bv0 = *(const f32x4*)(&bias[L][nt0 * 16 + lg * 4]);
        const f32x4 bv1 = *(const f32x4*)(&bias[L][nt1 * 16 + lg * 4]);
        if (L < 3) {
            float v0 = selu_f(a0[0] + bv0[0]);
            float v1 = selu_f(a0[1] + bv0[1]);
            float v2 = selu_f(a0[2] + bv0[2]);
            float v3 = selu_f(a0[3] + bv0[3]);
            float v4 = selu_f(a1[0] + bv1[0]);
            float v5 = selu_f(a1[1] + bv1[1]);
            float v6 = selu_f(a1[2] + bv1[2]);
            float v7 = selu_f(a1[3] + bv1[3]);
            u32x4 uu;
            uu.x = ((unsigned)f2bf(v1) << 16) | (unsigned)f2bf(v0);
            uu.y = ((unsigned)f2bf(v3) << 16) | (unsigned)f2bf(v2);
            uu.z = ((unsigned)f2bf(v5) << 16) | (unsigned)f2bf(v4);
            uu.w = ((unsigned)f2bf(v7) << 16) | (unsigned)f2bf(v6);
            char* ob = (char*)&zA[(L & 1) ^ 1][0];
            *(u32x4*)(ob + w * 1024 + lane * 16) = uu;
        } else if (m15 < 4) {
            f32x4 kv0, kv1;
#pragma unroll
            for (int r = 0; r < 4; ++r) { kv0[r] = a0[r] + bv0[r]; kv1[r] = a1[r] + bv1[r]; }
            *(f32x4*)(&k4[m15 * 264 + nt0 * 16 + lg * 4]) = kv0;
            *(f32x4*)(&k4[m15 * 264 + nt1 * 16 + lg * 4]) = kv1;
        }
    }
}

// ---------------- dopri5: 256 blocks (GE=4), 512 threads, 8 waves ---------
// LDS (~153 KiB) already limits to 1 block/CU, so allow the full 256-VGPR
// budget (8-wave block => HW cap 256) instead of the 128-cap that spilled.
__global__ __launch_bounds__(512, 1) void ode_kernel(
    const float* __restrict__ y0_buf, const float* __restrict__ times,
    const float* __restrict__ doses, const unsigned* __restrict__ WPK,
    const float* __restrict__ ob1, const float* __restrict__ ob2,
    const float* __restrict__ ob3, const float* __restrict__ ob4,
    const float* __restrict__ meta, const float* __restrict__ fcW,
    const float* __restrict__ fcb, float* __restrict__ out) {
    __shared__ unsigned w1lds[32768];        // W1 frags, 128 KiB
    __shared__ short zA[2][8 * 512];         // ping-pong frag-major activations, 2x8 KiB
    __shared__ float bias_lds[4][HD];        // 4 KiB
    __shared__ float k_lds4[4 * 264 + 16];   // padded rows, f32
    __shared__ float flg[4];

    const int tid  = threadIdx.x;
    const int lane = tid & 63;
    const int w    = tid >> 6;             // wave 0..7
    const int we   = w & 3;                // elem this wave mirrors/owns
    const bool owner = (w < 4);
    const int m15  = lane & 15;
    const int lg   = lane >> 4;
    const int b0   = blockIdx.x * GE;
    const int bidx = b0 + we;
    const int d0   = lane * 4;

    // ---- stage W1 frags into LDS (coalesced, once) ----
#pragma unroll
    for (int c = 0; c < 16; ++c) {
        int idx = c * 2048 + tid * 4;
        *(u32x4*)&w1lds[idx] = *(const u32x4*)(WPK + idx);
    }
    // ---- bias table ----
    if (tid < 256) { bias_lds[0][tid] = ob1[tid]; bias_lds[1][tid] = ob2[tid]; }
    else if (tid < 512) { int t = tid - 256; bias_lds[2][t] = ob3[t]; bias_lds[3][t] = ob4[t]; }
    // ---- zero both zA buffers (garbage rows stay finite forever) ----
    for (int zi = tid; zi < 2 * 8 * 256; zi += 512)
        ((unsigned*)zA)[zi] = 0u;

    // stage byte for y'(k=4q..4q+3, m=we), q=lane:
    //   ks=q>>3, lg=q&3, j=((q>>2)&1)*4 + i  -> 8B at:
    const int sbyte = (lane >> 3) * 1024 + (lane & 3) * 256 + we * 16 + ((lane >> 2) & 1) * 8;
    char* z0 = (char*)&zA[0][0];

    float y[4];
    {
        const float4 yv = *(const float4*)(y0_buf + bidx * HD + d0);
        y[0] = yv.x; y[1] = yv.y; y[2] = yv.z; y[3] = yv.w;
    }
    __syncthreads();   // staging visible

#define STAGE4(V0, V1, V2, V3)                                              \
    if (owner) {                                                            \
        u32x2 uu;                                                           \
        uu.x = ((unsigned)f2bf(V1) << 16) | (unsigned)f2bf(V0);             \
        uu.y = ((unsigned)f2bf(V3) << 16) | (unsigned)f2bf(V2);             \
        *(u32x2*)(z0 + sbyte) = uu;                                         \
    }

#define EVAL_READ(KV)                                                       \
    eval_mlp8(w1lds, WPK, bias_lds, zA, k_lds4, lane, w, m15, lg);          \
    __syncthreads();                                                        \
    {                                                                       \
        f32x4 kv = *(const f32x4*)(&k_lds4[we * 264 + d0]);                 \
        KV[0] = kv[0]; KV[1] = kv[1]; KV[2] = kv[2]; KV[3] = kv[3];         \
    }

    for (int j = 0; j < 4; ++j) {
        const float tt0 = times[(j * BATCH + bidx) * 2 + 0];
        const float t1  = times[(j * BATCH + bidx) * 2 + 1];
        const float ds  = doses[j * BATCH + bidx];
        const bool act0 = tt0 < t1;
        float ysv[4];
#pragma unroll
        for (int i = 0; i < 4; ++i) { ysv[i] = y[i]; y[i] += ds; }
        float t_s  = tt0;
        float dt_s = fmaxf(t1 - tt0, 1e-6f) * 0.1f;

        if (owner && lane == 0) flg[we] = act0 ? 1.f : 0.f;
        __syncthreads();
        bool anyact = (flg[0] + flg[1] + flg[2] + flg[3]) > 0.f;

        float k1[4], k2[4], k3[4], k4a[4], k5[4], k6[4], k7[4], y5[4], zt[4];
        if (anyact) {
            STAGE4(y[0], y[1], y[2], y[3]);
            EVAL_READ(k1);   // FSAL seed
        }

        for (int step = 0; step < 32 && anyact; ++step) {
            const bool act = t_s < t1;
            // NaN-propagating clip (matches jnp semantics)
            float d = dt_s;
            if (d < 0.f) d = 0.f;
            float rem = t1 - t_s;
            if (rem < 0.f) rem = 0.f;
            if (d > rem) d = rem;

#pragma unroll
            for (int i = 0; i < 4; ++i) zt[i] = y[i] + d * (A21f * k1[i]);
            STAGE4(zt[0], zt[1], zt[2], zt[3]);
            EVAL_READ(k2);
#pragma unroll
            for (int i = 0; i < 4; ++i) zt[i] = y[i] + d * (A31f * k1[i] + A32f * k2[i]);
            STAGE4(zt[0], zt[1], zt[2], zt[3]);
            EVAL_READ(k3);
#pragma unroll
            for (int i = 0; i < 4; ++i) zt[i] = y[i] + d * (A41f * k1[i] + A42f * k2[i] + A43f * k3[i]);
            STAGE4(zt[0], zt[1], zt[2], zt[3]);
            EVAL_READ(k4a);
#pragma unroll
            for (int i = 0; i < 4; ++i) zt[i] = y[i] + d * (A51f * k1[i] + A52f * k2[i] + A53f * k3[i] + A54f * k4a[i]);
            STAGE4(zt[0], zt[1], zt[2], zt[3]);
            EVAL_READ(k5);
#pragma unroll
            for (int i = 0; i < 4; ++i) zt[i] = y[i] + d * (A61f * k1[i] + A62f * k2[i] + A63f * k3[i] + A64f * k4a[i] + A65f * k5[i]);
            STAGE4(zt[0], zt[1], zt[2], zt[3]);
            EVAL_READ(k6);
#pragma unroll
            for (int i = 0; i < 4; ++i)
                y5[i] = y[i] + d * (BC0f * k1[i] + BC2f * k3[i] + BC3f * k4a[i] + BC4f * k5[i] + BC5f * k6[i]);
            STAGE4(y5[0], y5[1], y5[2], y5[3]);
            EVAL_READ(k7);

            float s = 0.f;
#pragma unroll
            for (int i = 0; i < 4; ++i) {
                float err = d * (EC0f * k1[i] + EC2f * k3[i] + EC3f * k4a[i] + EC4f * k5[i] + EC5f * k6[i] + EC6f * k7[i]);
                float sc = 1e-6f + 1e-3f * fmaxf(fabsf(y[i]), fabsf(y5[i]));
                float r = err / sc;
                s = fmaf(r, r, s);
            }
#pragma unroll
            for (int off = 32; off; off >>= 1) s += __shfl_xor(s, off, 64);
            const float en = sqrtf(s * (1.0f / HD));
            const bool accg = (en <= 1.0f) && act;
            if (accg) {
#pragma unroll
                for (int i = 0; i < 4; ++i) { y[i] = y5[i]; k1[i] = k7[i]; }  // FSAL
                t_s = t_s + d;
            }
            float fac = 0.9f * powf(en + 1e-10f, -0.2f);
            if (fac < 0.2f) fac = 0.2f;
            if (fac > 10.f) fac = 10.f;
            if (act) dt_s = fmaxf(d, 1e-8f) * fac;

            if (owner && lane == 0) flg[we] = (t_s < t1) ? 1.f : 0.f;
            __syncthreads();
            anyact = (flg[0] + flg[1] + flg[2] + flg[3]) > 0.f;
        }
#pragma unroll
        for (int i = 0; i < 4; ++i) y[i] = act0 ? y[i] : ysv[i];
    }

    // final FC: out[b] = y . fcW[0:256] + meta . fcW[256:260] + fcb
    float part = 0.f;
#pragma unroll
    for (int i = 0; i < 4; ++i) part = fmaf(y[i], fcW[d0 + i], part);
#pragma unroll
    for (int off = 32; off; off >>= 1) part += __shfl_xor(part, off, 64);
    if (owner && lane == 0) {
        float v = part + fcb[0];
#pragma unroll
        for (int m = 0; m < MMETA; ++m) v += meta[bidx * MMETA + m] * fcW[HD + m];
        out[bidx] = v;
    }
#undef STAGE4
#undef EVAL_READ
}

extern "C" void kernel_launch(void* const* d_in, const int* in_sizes, int n_in,
                              void* d_out, int out_size, void* d_ws, size_t ws_size,
                              hipStream_t stream) {
    const float* x     = (const float*)d_in[0];
    const float* meta  = (const float*)d_in[1];
    const float* eps   = (const float*)d_in[2];
    const float* times = (const float*)d_in[3];
    const float* doses = (const float*)d_in[4];
    const float* Wih   = (const float*)d_in[5];
    const float* Whh   = (const float*)d_in[6];
    const float* bih   = (const float*)d_in[7];
    const float* bhh   = (const float*)d_in[8];
    const float* eW1   = (const float*)d_in[9];
    const float* eb1   = (const float*)d_in[10];
    const float* eW2   = (const float*)d_in[11];
    const float* eb2   = (const float*)d_in[12];
    const float* oW1   = (const float*)d_in[13];
    const float* ob1   = (const float*)d_in[14];
    const float* oW2   = (const float*)d_in[15];
    const float* ob2   = (const float*)d_in[16];
    const float* oW3   = (const float*)d_in[17];
    const float* ob3   = (const float*)d_in[18];
    const float* oW4   = (const float*)d_in[19];
    const float* ob4   = (const float*)d_in[20];
    const float* fcW   = (const float*)d_in[21];
    const float* fcb   = (const float*)d_in[22];

    float* ws = (float*)d_ws;
    unsigned* WihF = (unsigned*)ws;               // u32 [48*256]         12288
    unsigned* WhhF = (unsigned*)(ws + 12288);     // u32 [48*8*256]       98304
    float*    eW1T = ws + 110592;                 // f32 [256][256]       65536
    float*    eW2T = ws + 176128;                 // f32 [256][512]       131072
    unsigned* oWPK = (unsigned*)(ws + 307200);    // u32 [4][16*8*256]    131072
    float*    hbuf = ws + 438272;                 // f32 [1024][256]      262144
    float*    y0b  = hbuf + 262144;               // f32 [1024][256]      262144

    pack_wih<<<12, 256, 0, stream>>>(Wih, WihF);
    pack_mfma_w<<<96, 256, 0, stream>>>(Whh, WhhF);
    transpose_kernel<<<dim3(1, 256), 256, 0, stream>>>(eW1, eW1T, 256, 256);
    transpose_kernel<<<dim3(1, 512), 256, 0, stream>>>(eW2, eW2T, 512, 256);
    pack_mfma_w<<<32, 256, 0, stream>>>(oW1, oWPK);
    pack_mfma_w<<<32, 256, 0, stream>>>(oW2, oWPK + 32768);
    pack_mfma_w<<<32, 256, 0, stream>>>(oW3, oWPK + 65536);
    pack_mfma_w<<<32, 256, 0, stream>>>(oW4, oWPK + 98304);

    gru_kernel<<<BATCH / 4, 512, 0, stream>>>(x, meta, WihF, WhhF, bih, bhh, hbuf);
    enc_kernel<<<BATCH / 8, 256, 0, stream>>>(hbuf, eps, eW1T, eb1, eW2T, eb2, y0b);
    ode_kernel<<<NBLK, 512, 0, stream>>>(y0b, times, doses, oWPK, ob1, ob2, ob3, ob4,
                                         meta, fcW, fcb, (float*)d_out);
}

// Round 13
// 1046.741 us; speedup vs baseline: 1.8130x; 1.2717x over previous
//
#include <hip/hip_runtime.h>
#include <math.h>

#define HD 256
#define BATCH 1024
#define NSTEPS 64
#define DIN 4
#define MMETA 4
#define GE 4
#define NBLK (BATCH / GE)

typedef short bf16x8 __attribute__((ext_vector_type(8)));
typedef float f32x4 __attribute__((ext_vector_type(4)));
typedef unsigned u32x2 __attribute__((ext_vector_type(2)));
typedef unsigned u32x4 __attribute__((ext_vector_type(4)));

#define F(x) ((float)(x))
#define A21f F(0.2)
#define A31f F(3.0/40.0)
#define A32f F(9.0/40.0)
#define A41f F(44.0/45.0)
#define A42f F(-56.0/15.0)
#define A43f F(32.0/9.0)
#define A51f F(19372.0/6561.0)
#define A52f F(-25360.0/2187.0)
#define A53f F(64448.0/6561.0)
#define A54f F(-212.0/729.0)
#define A61f F(9017.0/3168.0)
#define A62f F(-355.0/33.0)
#define A63f F(46732.0/5247.0)
#define A64f F(49.0/176.0)
#define A65f F(-5103.0/18656.0)
#define BC0f F(35.0/384.0)
#define BC2f F(500.0/1113.0)
#define BC3f F(125.0/192.0)
#define BC4f F(-2187.0/6784.0)
#define BC5f F(11.0/84.0)
#define EC0f F(35.0/384.0 - 5179.0/57600.0)
#define EC2f F(500.0/1113.0 - 7571.0/16695.0)
#define EC3f F(125.0/192.0 - 393.0/640.0)
#define EC4f F(-2187.0/6784.0 + 92097.0/339200.0)
#define EC5f F(11.0/84.0 - 187.0/2100.0)
#define EC6f F(-1.0/40.0)

#define SELU_SCALE 1.0507009873554805f
#define SELU_SA    1.7580993408473766f   // scale*alpha

__device__ __forceinline__ unsigned short f2bf(float f) {
    unsigned u = __float_as_uint(f);
    return (unsigned short)((u + 0x7fffu + ((u >> 16) & 1u)) >> 16);
}

__device__ __forceinline__ float selu_f(float v) {
    return v > 0.f ? SELU_SCALE * v : fmaf(SELU_SA, __expf(v), -SELU_SA);
}

// Frag-major activation layout: element (m,k) at byte ks*1024 + lg*256 + m*16 + j*2
// (k = ks*32 + (j>>2)*16 + lg*4 + (j&3)). A-fragment read (ks, lane) = byte
// ks*1024 + lane*16 -> contiguous (verified R11: conflicts 64M -> 4.5M).

// ---------------- generic transpose: in[R][C] -> out[C][R] ----------------
__global__ void transpose_kernel(const float* __restrict__ in, float* __restrict__ out,
                                 int R, int C) {
    int c = blockIdx.x * 256 + threadIdx.x;
    int r = blockIdx.y;
    if (c < C) out[c * R + r] = in[r * C + c];
}

// ---- pack W[NT*16][256] f32 into per-lane MFMA fragments -----------------
__global__ void pack_mfma_w(const float* __restrict__ W, unsigned* __restrict__ out) {
    int t = blockIdx.x * 256 + threadIdx.x;
    int lane = t & 63, ks = (t >> 6) & 7, nt = t >> 9;
    int n = nt * 16 + (lane & 15), lg = lane >> 4;
    const float* wr = W + n * HD;
    u32x4 v;
#pragma unroll
    for (int r = 0; r < 4; ++r) {
        int j0 = 2 * r, j1 = 2 * r + 1;
        int k0 = ks * 32 + ((j0 >> 2) << 4) + lg * 4 + (j0 & 3);
        int k1 = ks * 32 + ((j1 >> 2) << 4) + lg * 4 + (j1 & 3);
        v[r] = ((unsigned)f2bf(wr[k1]) << 16) | (unsigned)f2bf(wr[k0]);
    }
    *(u32x4*)(out + t * 4) = v;
}

// ---- pack Wih[768][8] into k=0..7-only fragments (48 nt, 1 ks tile) ------
__global__ void pack_wih(const float* __restrict__ W, unsigned* __restrict__ out) {
    int t = blockIdx.x * 256 + threadIdx.x;
    int lane = t & 63, nt = t >> 6;
    int n = nt * 16 + (lane & 15), lg = lane >> 4;
    u32x4 v;
#pragma unroll
    for (int r = 0; r < 4; ++r) {
        int j0 = 2 * r, j1 = 2 * r + 1;
        int k0 = ((j0 >> 2) << 4) + lg * 4 + (j0 & 3);
        int k1 = ((j1 >> 2) << 4) + lg * 4 + (j1 & 3);
        unsigned a = (k0 < 8) ? (unsigned)f2bf(W[n * 8 + k0]) : 0u;
        unsigned b = (k1 < 8) ? (unsigned)f2bf(W[n * 8 + k1]) : 0u;
        v[r] = (b << 16) | a;
    }
    *(u32x4*)(out + t * 4) = v;
}

// ---------------- GRU via MFMA: 256 blocks (G=4), 512 threads -------------
__global__ __launch_bounds__(512, 2) void gru_kernel(
    const float* __restrict__ x, const float* __restrict__ meta,
    const unsigned* __restrict__ WihF, const unsigned* __restrict__ WhhF,
    const float* __restrict__ bih, const float* __restrict__ bhh,
    float* __restrict__ h_out) {
    __shared__ short zB[9 * 512];       // frag-major, 9 ks-tiles (h + xm), 9216 B
    __shared__ float ghs[768][4];
    __shared__ float ghx[256][4];
    __shared__ float bsum[512], binn[256], bhn[256];

    const int tid  = threadIdx.x;
    const int lane = tid & 63;
    const int w    = tid >> 6;          // wave 0..7
    const int m15  = lane & 15;
    const int lg   = lane >> 4;
    const int b0   = blockIdx.x * 4;

    if (tid < 512) bsum[tid] = bih[tid] + bhh[tid];
    if (tid < 256) { binn[tid] = bih[512 + tid]; bhn[tid] = bhh[512 + tid]; }
    for (int i = tid; i < 9 * 256; i += 512) ((unsigned*)zB)[i] = 0u;

    // byte position (minus m*16) of h element k=tid in frag-major layout
    const int hpb = (tid >> 5) * 1024 + ((tid >> 2) & 3) * 256 +
                    ((((tid >> 4) & 1) * 4 + (tid & 3)) * 2);

    float h_own[4] = {0.f, 0.f, 0.f, 0.f};
    __syncthreads();

    // stage xm for step 0
    if (tid < 32) {
        int c = tid & 7, m = tid >> 3;
        float v = (c < 4) ? x[((b0 + m) * NSTEPS + 0) * DIN + c]
                          : meta[(b0 + m) * MMETA + (c - 4)];
        *(short*)((char*)zB + 8192 + (c >> 2) * 256 + m * 16 + (c & 3) * 2) = (short)f2bf(v);
    }

    for (int n = 0; n < NSTEPS; ++n) {
        __syncthreads();                // barrier A: zB (h + xm) ready
        bf16x8 zf[9];
#pragma unroll
        for (int ks = 0; ks < 9; ++ks)
            zf[ks] = *(const bf16x8*)((const char*)zB + ks * 1024 + lane * 16);
#pragma unroll
        for (int jn = 0; jn < 6; ++jn) {
            const int nt = w * 6 + jn;
            const unsigned* bp = WhhF + (nt * 8) * 256 + lane * 4;
            f32x4 acc = {0.f, 0.f, 0.f, 0.f};
#pragma unroll
            for (int ks = 0; ks < 8; ++ks) {
                bf16x8 wf = *(const bf16x8*)(bp + ks * 256);
                acc = __builtin_amdgcn_mfma_f32_16x16x32_bf16(wf, zf[ks], acc, 0, 0, 0);
            }
            bf16x8 wih = *(const bf16x8*)(WihF + nt * 256 + lane * 4);
            if (nt < 32) {
                acc = __builtin_amdgcn_mfma_f32_16x16x32_bf16(wih, zf[8], acc, 0, 0, 0);
                if (m15 < 4) {
#pragma unroll
                    for (int r = 0; r < 4; ++r) ghs[nt * 16 + lg * 4 + r][m15] = acc[r];
                }
            } else {
                f32x4 ax = {0.f, 0.f, 0.f, 0.f};
                ax = __builtin_amdgcn_mfma_f32_16x16x32_bf16(wih, zf[8], ax, 0, 0, 0);
                if (m15 < 4) {
#pragma unroll
                    for (int r = 0; r < 4; ++r) {
                        int row = nt * 16 + lg * 4 + r;
                        ghs[row][m15] = acc[r];
                        ghx[row - 512][m15] = ax[r];
                    }
                }
            }
        }
        __syncthreads();                // barrier B: gh ready; zB reads done
        if (tid < 256) {
            f32x4 s0 = *(const f32x4*)(&ghs[tid][0]);
            f32x4 s1 = *(const f32x4*)(&ghs[tid + 256][0]);
            f32x4 hn = *(const f32x4*)(&ghs[tid + 512][0]);
            f32x4 in = *(const f32x4*)(&ghx[tid][0]);
            float bs0 = bsum[tid], bs1 = bsum[tid + 256];
            float bi2 = binn[tid], bh2 = bhn[tid];
#pragma unroll
            for (int m = 0; m < 4; ++m) {
                float rr = 1.f / (1.f + expf(-(s0[m] + bs0)));
                float zz = 1.f / (1.f + expf(-(s1[m] + bs1)));
                float nn = tanhf((in[m] + bi2) + rr * (hn[m] + bh2));
                h_own[m] = (1.f - zz) * nn + zz * h_own[m];
                *(short*)((char*)zB + hpb + m * 16) = (short)f2bf(h_own[m]);
            }
        }
        if (tid < 32 && n + 1 < NSTEPS) {
            int c = tid & 7, m = tid >> 3;
            float v = (c < 4) ? x[((b0 + m) * NSTEPS + (n + 1)) * DIN + c]
                              : meta[(b0 + m) * MMETA + (c - 4)];
            *(short*)((char*)zB + 8192 + (c >> 2) * 256 + m * 16 + (c & 3) * 2) = (short)f2bf(v);
        }
    }
    if (tid < 256) {
#pragma unroll
        for (int m = 0; m < 4; ++m) h_out[(b0 + m) * HD + tid] = h_own[m];
    }
}

// ---------------- encoder + reparameterization (G=8, 128 blocks) ----------
__global__ __launch_bounds__(256) void enc_kernel(
    const float* __restrict__ h_buf, const float* __restrict__ eps,
    const float* __restrict__ W1T, const float* __restrict__ b1,
    const float* __restrict__ W2T, const float* __restrict__ b2,
    float* __restrict__ y0_buf) {
    __shared__ float zsh[HD][8];
    const int tid = threadIdx.x;
    const int b0 = blockIdx.x * 8;
#pragma unroll
    for (int g = 0; g < 8; ++g) zsh[tid][g] = h_buf[(b0 + g) * HD + tid];
    __syncthreads();
    float acc[8];
    {
        float bb = b1[tid];
#pragma unroll
        for (int g = 0; g < 8; ++g) acc[g] = bb;
        for (int k = 0; k < HD; k += 4) {
#pragma unroll
            for (int u = 0; u < 4; ++u) {
                float w = W1T[(k + u) * HD + tid];
                const float4 za = *(const float4*)(&zsh[k + u][0]);
                const float4 zb = *(const float4*)(&zsh[k + u][4]);
                acc[0] = fmaf(w, za.x, acc[0]); acc[1] = fmaf(w, za.y, acc[1]);
                acc[2] = fmaf(w, za.z, acc[2]); acc[3] = fmaf(w, za.w, acc[3]);
                acc[4] = fmaf(w, zb.x, acc[4]); acc[5] = fmaf(w, zb.y, acc[5]);
                acc[6] = fmaf(w, zb.z, acc[6]); acc[7] = fmaf(w, zb.w, acc[7]);
            }
        }
    }
    __syncthreads();
#pragma unroll
    for (int g = 0; g < 8; ++g) zsh[tid][g] = fmaxf(acc[g], 0.f);
    __syncthreads();
    float am[8], as[8];
    {
        float bm = b2[tid], bs = b2[tid + HD];
#pragma unroll
        for (int g = 0; g < 8; ++g) { am[g] = bm; as[g] = bs; }
        for (int k = 0; k < HD; k += 4) {
#pragma unroll
            for (int u = 0; u < 4; ++u) {
                float wm = W2T[(k + u) * 512 + tid];
                float ws2 = W2T[(k + u) * 512 + HD + tid];
                const float4 za = *(const float4*)(&zsh[k + u][0]);
                const float4 zb = *(const float4*)(&zsh[k + u][4]);
                am[0] = fmaf(wm, za.x, am[0]); am[1] = fmaf(wm, za.y, am[1]);
                am[2] = fmaf(wm, za.z, am[2]); am[3] = fmaf(wm, za.w, am[3]);
                am[4] = fmaf(wm, zb.x, am[4]); am[5] = fmaf(wm, zb.y, am[5]);
                am[6] = fmaf(wm, zb.z, am[6]); am[7] = fmaf(wm, zb.w, am[7]);
                as[0] = fmaf(ws2, za.x, as[0]); as[1] = fmaf(ws2, za.y, as[1]);
                as[2] = fmaf(ws2, za.z, as[2]); as[3] = fmaf(ws2, za.w, as[3]);
                as[4] = fmaf(ws2, zb.x, as[4]); as[5] = fmaf(ws2, zb.y, as[5]);
                as[6] = fmaf(ws2, zb.z, as[6]); as[7] = fmaf(ws2, zb.w, as[7]);
            }
        }
    }
#pragma unroll
    for (int g = 0; g < 8; ++g)
        y0_buf[(b0 + g) * HD + tid] = eps[(b0 + g) * HD + tid] * as[g] + am[g];
}

// ---------- MFMA 4-layer MLP: W1 LDS, W2/W3 register-resident, W4 L2 ------
__device__ __forceinline__ void eval_mlp8(
    const bf16x8 (&wr2)[2][8], const bf16x8 (&wr3)[2][8],
    const unsigned* __restrict__ w1l, const unsigned* __restrict__ WPK,
    const float (*bias)[HD], short (*zA)[8 * 512], float* __restrict__ k4,
    int lane, int w, int m15, int lg) {
    const int nt0 = 2 * w, nt1 = 2 * w + 1;
#pragma unroll
    for (int L = 0; L < 4; ++L) {
        __syncthreads();   // staged y' / previous epilogue visible; WAR safe
        const char* ibp = (const char*)&zA[L & 1][0];
        f32x4 a0 = {0.f, 0.f, 0.f, 0.f}, a1 = {0.f, 0.f, 0.f, 0.f};
#pragma unroll
        for (int ks = 0; ks < 8; ++ks) {
            bf16x8 zq = *(const bf16x8*)(ibp + ks * 1024 + lane * 16);
            bf16x8 wf0, wf1;
            if (L == 0) {
                wf0 = *(const bf16x8*)(w1l + (nt0 * 8 + ks) * 256 + lane * 4);
                wf1 = *(const bf16x8*)(w1l + (nt1 * 8 + ks) * 256 + lane * 4);
            } else if (L == 1) {
                wf0 = wr2[0][ks];
                wf1 = wr2[1][ks];
            } else if (L == 2) {
                wf0 = wr3[0][ks];
                wf1 = wr3[1][ks];
            } else {
                wf0 = *(const bf16x8*)(WPK + ((48 + nt0) * 8 + ks) * 256 + lane * 4);
                wf1 = *(const bf16x8*)(WPK + ((48 + nt1) * 8 + ks) * 256 + lane * 4);
            }
            a0 = __builtin_amdgcn_mfma_f32_16x16x32_bf16(wf0, zq, a0, 0, 0, 0);
            a1 = __builtin_amdgcn_mfma_f32_16x16x32_bf16(wf1, zq, a1, 0, 0, 0);
        }
        // D^T: lane holds col m=m15, rows n = nt*16 + lg*4 + r.
        const f32x4 bv0 = *(const f32x4*)(&bias[L][nt0 * 16 + lg * 4]);
        const f32x4 bv1 = *(const f32x4*)(&bias[L][nt1 * 16 + lg * 4]);
        if (L < 3) {
            float v0 = selu_f(a0[0] + bv0[0]);
            float v1 = selu_f(a0[1] + bv0[1]);
            float v2 = selu_f(a0[2] + bv0[2]);
            float v3 = selu_f(a0[3] + bv0[3]);
            float v4 = selu_f(a1[0] + bv1[0]);
            float v5 = selu_f(a1[1] + bv1[1]);
            float v6 = selu_f(a1[2] + bv1[2]);
            float v7 = selu_f(a1[3] + bv1[3]);
            u32x4 uu;
            uu.x = ((unsigned)f2bf(v1) << 16) | (unsigned)f2bf(v0);
            uu.y = ((unsigned)f2bf(v3) << 16) | (unsigned)f2bf(v2);
            uu.z = ((unsigned)f2bf(v5) << 16) | (unsigned)f2bf(v4);
            uu.w = ((unsigned)f2bf(v7) << 16) | (unsigned)f2bf(v6);
            char* ob = (char*)&zA[(L & 1) ^ 1][0];
            *(u32x4*)(ob + w * 1024 + lane * 16) = uu;
        } else if (m15 < 4) {
            f32x4 kv0, kv1;
#pragma unroll
            for (int r = 0; r < 4; ++r) { kv0[r] = a0[r] + bv0[r]; kv1[r] = a1[r] + bv1[r]; }
            *(f32x4*)(&k4[m15 * 264 + nt0 * 16 + lg * 4]) = kv0;
            *(f32x4*)(&k4[m15 * 264 + nt1 * 16 + lg * 4]) = kv1;
        }
    }
}

// ---------------- dopri5: 256 blocks (GE=4), 512 threads, 8 waves ---------
// LDS (~153 KiB) limits to 1 block/CU; allow full 256-reg budget.
// Waves 0-3 own elems 0-3 (controller + staging); waves 4-7 are compute-only.
__global__ __launch_bounds__(512, 1) void ode_kernel(
    const float* __restrict__ y0_buf, const float* __restrict__ times,
    const float* __restrict__ doses, const unsigned* __restrict__ WPK,
    const float* __restrict__ ob1, const float* __restrict__ ob2,
    const float* __restrict__ ob3, const float* __restrict__ ob4,
    const float* __restrict__ meta, const float* __restrict__ fcW,
    const float* __restrict__ fcb, float* __restrict__ out) {
    __shared__ unsigned w1lds[32768];        // W1 frags, 128 KiB
    __shared__ short zA[2][8 * 512];         // ping-pong frag-major activations, 2x8 KiB
    __shared__ float bias_lds[4][HD];        // 4 KiB
    __shared__ float k_lds4[4 * 264 + 16];   // padded rows, f32
    __shared__ float flg[4];

    const int tid  = threadIdx.x;
    const int lane = tid & 63;
    const int w    = tid >> 6;             // wave 0..7
    const int we   = w & 3;
    const bool owner = (w < 4);
    const int m15  = lane & 15;
    const int lg   = lane >> 4;
    const int b0   = blockIdx.x * GE;
    const int bidx = b0 + we;
    const int d0   = lane * 4;

    // ---- stage W1 frags into LDS (coalesced, once) ----
#pragma unroll
    for (int c = 0; c < 16; ++c) {
        int idx = c * 2048 + tid * 4;
        *(u32x4*)&w1lds[idx] = *(const u32x4*)(WPK + idx);
    }
    // ---- bias table ----
    if (tid < 256) { bias_lds[0][tid] = ob1[tid]; bias_lds[1][tid] = ob2[tid]; }
    else if (tid < 512) { int t = tid - 256; bias_lds[2][t] = ob3[t]; bias_lds[3][t] = ob4[t]; }
    // ---- zero both zA buffers (garbage rows stay finite forever) ----
    for (int zi = tid; zi < 2 * 8 * 256; zi += 512)
        ((unsigned*)zA)[zi] = 0u;

    // ---- W2, W3 fragments register-resident (2 nt per wave; unified VGPR/AGPR) ----
    bf16x8 wr2[2][8], wr3[2][8];
#pragma unroll
    for (int jj = 0; jj < 2; ++jj)
#pragma unroll
        for (int ks = 0; ks < 8; ++ks) {
            wr2[jj][ks] = *(const bf16x8*)(WPK + ((16 + 2 * w + jj) * 8 + ks) * 256 + lane * 4);
            wr3[jj][ks] = *(const bf16x8*)(WPK + ((32 + 2 * w + jj) * 8 + ks) * 256 + lane * 4);
        }

    // stage byte for y'(k=4q..4q+3, m=we), q=lane
    const int sbyte = (lane >> 3) * 1024 + (lane & 3) * 256 + we * 16 + ((lane >> 2) & 1) * 8;
    char* z0 = (char*)&zA[0][0];

    float y[4] = {0.f, 0.f, 0.f, 0.f};
    if (owner) {
        const float4 yv = *(const float4*)(y0_buf + bidx * HD + d0);
        y[0] = yv.x; y[1] = yv.y; y[2] = yv.z; y[3] = yv.w;
    }
    __syncthreads();   // staging visible

#define STAGE4(V0, V1, V2, V3)                                              \
    {                                                                       \
        u32x2 uu;                                                           \
        uu.x = ((unsigned)f2bf(V1) << 16) | (unsigned)f2bf(V0);             \
        uu.y = ((unsigned)f2bf(V3) << 16) | (unsigned)f2bf(V2);             \
        *(u32x2*)(z0 + sbyte) = uu;                                         \
    }

#define EVAL_READ(KV)                                                       \
    eval_mlp8(wr2, wr3, w1lds, WPK, bias_lds, zA, k_lds4, lane, w, m15, lg);\
    __syncthreads();                                                        \
    if (owner) {                                                            \
        f32x4 kv = *(const f32x4*)(&k_lds4[we * 264 + d0]);                 \
        KV[0] = kv[0]; KV[1] = kv[1]; KV[2] = kv[2]; KV[3] = kv[3];         \
    }

    for (int j = 0; j < 4; ++j) {
        float t1 = 0.f, t_s = 0.f, dt_s = 0.f, ysv[4];
        bool act0 = false;
        if (owner) {
            const float tt0 = times[(j * BATCH + bidx) * 2 + 0];
            t1 = times[(j * BATCH + bidx) * 2 + 1];
            const float ds = doses[j * BATCH + bidx];
            act0 = tt0 < t1;
#pragma unroll
            for (int i = 0; i < 4; ++i) { ysv[i] = y[i]; y[i] += ds; }
            t_s = tt0;
            dt_s = fmaxf(t1 - tt0, 1e-6f) * 0.1f;
            if (lane == 0) flg[we] = act0 ? 1.f : 0.f;
        }
        __syncthreads();
        bool anyact = (flg[0] + flg[1] + flg[2] + flg[3]) > 0.f;

        float k1[4], k2[4], k3[4], k4a[4], k5[4], k6[4], k7[4], y5[4], zt[4];
        if (anyact) {
            if (owner) STAGE4(y[0], y[1], y[2], y[3]);
            EVAL_READ(k1);   // FSAL seed
        }

        for (int step = 0; step < 32 && anyact; ++step) {
            bool act = false; float d = 0.f;
            if (owner) {
                act = t_s < t1;
                // NaN-propagating clip (matches jnp semantics)
                d = dt_s;
                if (d < 0.f) d = 0.f;
                float rem = t1 - t_s;
                if (rem < 0.f) rem = 0.f;
                if (d > rem) d = rem;
#pragma unroll
                for (int i = 0; i < 4; ++i) zt[i] = y[i] + d * (A21f * k1[i]);
                STAGE4(zt[0], zt[1], zt[2], zt[3]);
            }
            EVAL_READ(k2);
            if (owner) {
#pragma unroll
                for (int i = 0; i < 4; ++i) zt[i] = y[i] + d * (A31f * k1[i] + A32f * k2[i]);
                STAGE4(zt[0], zt[1], zt[2], zt[3]);
            }
            EVAL_READ(k3);
            if (owner) {
#pragma unroll
                for (int i = 0; i < 4; ++i) zt[i] = y[i] + d * (A41f * k1[i] + A42f * k2[i] + A43f * k3[i]);
                STAGE4(zt[0], zt[1], zt[2], zt[3]);
            }
            EVAL_READ(k4a);
            if (owner) {
#pragma unroll
                for (int i = 0; i < 4; ++i) zt[i] = y[i] + d * (A51f * k1[i] + A52f * k2[i] + A53f * k3[i] + A54f * k4a[i]);
                STAGE4(zt[0], zt[1], zt[2], zt[3]);
            }
            EVAL_READ(k5);
            if (owner) {
#pragma unroll
                for (int i = 0; i < 4; ++i) zt[i] = y[i] + d * (A61f * k1[i] + A62f * k2[i] + A63f * k3[i] + A64f * k4a[i] + A65f * k5[i]);
                STAGE4(zt[0], zt[1], zt[2], zt[3]);
            }
            EVAL_READ(k6);
            if (owner) {
#pragma unroll
                for (int i = 0; i < 4; ++i)
                    y5[i] = y[i] + d * (BC0f * k1[i] + BC2f * k3[i] + BC3f * k4a[i] + BC4f * k5[i] + BC5f * k6[i]);
                STAGE4(y5[0], y5[1], y5[2], y5[3]);
            }
            EVAL_READ(k7);

            if (owner) {
                float s = 0.f;
#pragma unroll
                for (int i = 0; i < 4; ++i) {
                    float err = d * (EC0f * k1[i] + EC2f * k3[i] + EC3f * k4a[i] + EC4f * k5[i] + EC5f * k6[i] + EC6f * k7[i]);
                    float sc = 1e-6f + 1e-3f * fmaxf(fabsf(y[i]), fabsf(y5[i]));
                    float r = err / sc;
                    s = fmaf(r, r, s);
                }
#pragma unroll
                for (int off = 32; off; off >>= 1) s += __shfl_xor(s, off, 64);
                const float en = sqrtf(s * (1.0f / HD));
                const bool accg = (en <= 1.0f) && act;
                if (accg) {
#pragma unroll
                    for (int i = 0; i < 4; ++i) { y[i] = y5[i]; k1[i] = k7[i]; }  // FSAL
                    t_s = t_s + d;
                }
                float fac = 0.9f * powf(en + 1e-10f, -0.2f);
                if (fac < 0.2f) fac = 0.2f;
                if (fac > 10.f) fac = 10.f;
                if (act) dt_s = fmaxf(d, 1e-8f) * fac;
                if (lane == 0) flg[we] = (t_s < t1) ? 1.f : 0.f;
            }
            __syncthreads();
            anyact = (flg[0] + flg[1] + flg[2] + flg[3]) > 0.f;
        }
        if (owner) {
#pragma unroll
            for (int i = 0; i < 4; ++i) y[i] = act0 ? y[i] : ysv[i];
        }
    }

    // final FC: out[b] = y . fcW[0:256] + meta . fcW[256:260] + fcb
    if (owner) {
        float part = 0.f;
#pragma unroll
        for (int i = 0; i < 4; ++i) part = fmaf(y[i], fcW[d0 + i], part);
#pragma unroll
        for (int off = 32; off; off >>= 1) part += __shfl_xor(part, off, 64);
        if (lane == 0) {
            float v = part + fcb[0];
#pragma unroll
            for (int m = 0; m < MMETA; ++m) v += meta[bidx * MMETA + m] * fcW[HD + m];
            out[bidx] = v;
        }
    }
#undef STAGE4
#undef EVAL_READ
}

extern "C" void kernel_launch(void* const* d_in, const int* in_sizes, int n_in,
                              void* d_out, int out_size, void* d_ws, size_t ws_size,
                              hipStream_t stream) {
    const float* x     = (const float*)d_in[0];
    const float* meta  = (const float*)d_in[1];
    const float* eps   = (const float*)d_in[2];
    const float* times = (const float*)d_in[3];
    const float* doses = (const float*)d_in[4];
    const float* Wih   = (const float*)d_in[5];
    const float* Whh   = (const float*)d_in[6];
    const float* bih   = (const float*)d_in[7];
    const float* bhh   = (const float*)d_in[8];
    const float* eW1   = (const float*)d_in[9];
    const float* eb1   = (const float*)d_in[10];
    const float* eW2   = (const float*)d_in[11];
    const float* eb2   = (const float*)d_in[12];
    const float* oW1   = (const float*)d_in[13];
    const float* ob1   = (const float*)d_in[14];
    const float* oW2   = (const float*)d_in[15];
    const float* ob2   = (const float*)d_in[16];
    const float* oW3   = (const float*)d_in[17];
    const float* ob3   = (const float*)d_in[18];
    const float* oW4   = (const float*)d_in[19];
    const float* ob4   = (const float*)d_in[20];
    const float* fcW   = (const float*)d_in[21];
    const float* fcb   = (const float*)d_in[22];

    float* ws = (float*)d_ws;
    unsigned* WihF = (unsigned*)ws;               // u32 [48*256]         12288
    unsigned* WhhF = (unsigned*)(ws + 12288);     // u32 [48*8*256]       98304
    float*    eW1T = ws + 110592;                 // f32 [256][256]       65536
    float*    eW2T = ws + 176128;                 // f32 [256][512]       131072
    unsigned* oWPK = (unsigned*)(ws + 307200);    // u32 [4][16*8*256]    131072
    float*    hbuf = ws + 438272;                 // f32 [1024][256]      262144
    float*    y0b  = hbuf + 262144;               // f32 [1024][256]      262144

    pack_wih<<<12, 256, 0, stream>>>(Wih, WihF);
    pack_mfma_w<<<96, 256, 0, stream>>>(Whh, WhhF);
    transpose_kernel<<<dim3(1, 256), 256, 0, stream>>>(eW1, eW1T, 256, 256);
    transpose_kernel<<<dim3(1, 512), 256, 0, stream>>>(eW2, eW2T, 512, 256);
    pack_mfma_w<<<32, 256, 0, stream>>>(oW1, oWPK);
    pack_mfma_w<<<32, 256, 0, stream>>>(oW2, oWPK + 32768);
    pack_mfma_w<<<32, 256, 0, stream>>>(oW3, oWPK + 65536);
    pack_mfma_w<<<32, 256, 0, stream>>>(oW4, oWPK + 98304);

    gru_kernel<<<BATCH / 4, 512, 0, stream>>>(x, meta, WihF, WhhF, bih, bhh, hbuf);
    enc_kernel<<<BATCH / 8, 256, 0, stream>>>(hbuf, eps, eW1T, eb1, eW2T, eb2, y0b);
    ode_kernel<<<NBLK, 512, 0, stream>>>(y0b, times, doses, oWPK, ob1, ob2, ob3, ob4,
                                         meta, fcW, fcb, (float*)d_out);
}